// Round 1
// baseline (1292.079 us; speedup 1.0000x reference)
//
#include <hip/hip_runtime.h>
#include <math.h>

#define NN 16384
#define EE 262144
#define BB 8
#define TT 32
#define DD 256
#define HH 8
#define HDD 32

typedef __bf16 bf16;
typedef __bf16 bf16x8 __attribute__((ext_vector_type(8)));
typedef __bf16 bf16x4 __attribute__((ext_vector_type(4)));
typedef float f32x4 __attribute__((ext_vector_type(4)));

#define GM_F32 0
#define GM_BF16 1
#define GM_GELU 2
#define GM_RES 3

__device__ __forceinline__ float gelu_f(float v) {
  return 0.5f * v * (1.f + erff(v * 0.70710678118654752440f));
}

// ---------------- weight cast (9 weights, one launch) ----------------
struct Cast9 {
  const float* src[9];
  bf16* dst[9];
  int blk_start[10];
};

__global__ __launch_bounds__(256) void cast9(Cast9 c) {
  int blk = blockIdx.x;
  int s = 0;
  while (blk >= c.blk_start[s + 1]) ++s;
  int local = blk - c.blk_start[s];
  int i = local * 1024 + threadIdx.x * 4;
  const float4 f = *(const float4*)(c.src[s] + i);
  bf16x4 o;
  o[0] = (bf16)f.x; o[1] = (bf16)f.y; o[2] = (bf16)f.z; o[3] = (bf16)f.w;
  *(bf16x4*)(c.dst[s] + i) = o;
}

__global__ __launch_bounds__(256) void cast_f32_bf16_k(const float* __restrict__ src,
                                                       bf16* __restrict__ dst, int n) {
  int i = blockIdx.x * 256 + threadIdx.x;
  if (i < n) dst[i] = (bf16)src[i];
}

// ---------------- rowwise LayerNorm (f32 in, bf16 out, optional gelu) ----------------
__global__ __launch_bounds__(256) void ln_rows(const float* __restrict__ in,
                                               const float* __restrict__ g,
                                               const float* __restrict__ b,
                                               bf16* __restrict__ out, int C, int do_gelu) {
  int row = blockIdx.x;
  const float* x = in + (size_t)row * C;
  float s = 0.f, s2 = 0.f;
  for (int c = threadIdx.x; c < C; c += 256) {
    float v = x[c];
    s += v;
    s2 += v * v;
  }
#pragma unroll
  for (int o = 32; o > 0; o >>= 1) {
    s += __shfl_down(s, o, 64);
    s2 += __shfl_down(s2, o, 64);
  }
  __shared__ float red[8];
  int wv = threadIdx.x >> 6;
  if ((threadIdx.x & 63) == 0) { red[wv] = s; red[4 + wv] = s2; }
  __syncthreads();
  s = red[0] + red[1] + red[2] + red[3];
  s2 = red[4] + red[5] + red[6] + red[7];
  float m = s / C;
  float rs = rsqrtf(s2 / C - m * m + 1e-5f);
  for (int c = threadIdx.x; c < C; c += 256) {
    float v = (x[c] - m) * rs * g[c] + b[c];
    if (do_gelu) v = gelu_f(v);
    out[(size_t)row * C + c] = (bf16)v;
  }
}

// ---------------- CSR build ----------------
__global__ __launch_bounds__(256) void deg_count(const int* __restrict__ ei, int* __restrict__ deg) {
  int e = blockIdx.x * 256 + threadIdx.x;
  if (e < EE) atomicAdd(&deg[ei[EE + e]], 1);
}

__global__ __launch_bounds__(256) void chunk_sum(const int* __restrict__ deg, int* __restrict__ psum) {
  __shared__ int sh[256];
  sh[threadIdx.x] = deg[blockIdx.x * 256 + threadIdx.x];
  __syncthreads();
  for (int o = 128; o > 0; o >>= 1) {
    if (threadIdx.x < o) sh[threadIdx.x] += sh[threadIdx.x + o];
    __syncthreads();
  }
  if (threadIdx.x == 0) psum[blockIdx.x] = sh[0];
}

__global__ void scan_psum(const int* __restrict__ psum, int* __restrict__ pbase) {
  if (threadIdx.x == 0) {
    int acc = 0;
    for (int i = 0; i < 64; ++i) { pbase[i] = acc; acc += psum[i]; }
  }
}

__global__ __launch_bounds__(256) void chunk_scan(const int* __restrict__ deg,
                                                  const int* __restrict__ pbase,
                                                  int* __restrict__ offs, int* __restrict__ woff) {
  __shared__ int sh[256];
  int gi = blockIdx.x * 256 + threadIdx.x;
  int v = deg[gi];
  sh[threadIdx.x] = v;
  __syncthreads();
  for (int o = 1; o < 256; o <<= 1) {
    int t = (threadIdx.x >= o) ? sh[threadIdx.x - o] : 0;
    __syncthreads();
    sh[threadIdx.x] += t;
    __syncthreads();
  }
  int excl = pbase[blockIdx.x] + sh[threadIdx.x] - v;
  offs[gi] = excl;
  woff[gi] = excl;
  if (blockIdx.x == 63 && threadIdx.x == 255) offs[NN] = pbase[63] + sh[255];
}

__global__ __launch_bounds__(256) void csr_fill(const int* __restrict__ ei, int* __restrict__ woff,
                                                int* __restrict__ csr) {
  int e = blockIdx.x * 256 + threadIdx.x;
  if (e < EE) {
    int d = ei[EE + e];
    int p = atomicAdd(&woff[d], 1);
    csr[p] = e;
  }
}

// GINE aggregation: block per node, thread per channel. hin = (1+eps)*xn + sum relu(xn[src]+ea)
__global__ __launch_bounds__(256) void gine_agg(const int* __restrict__ ei,
                                                const float* __restrict__ eattr,
                                                const bf16* __restrict__ xn,
                                                const int* __restrict__ offs,
                                                const int* __restrict__ csr,
                                                const float* __restrict__ epsp,
                                                bf16* __restrict__ hin) {
  int n = blockIdx.x, t = threadIdx.x;
  int s0 = offs[n], s1 = offs[n + 1];
  float acc = 0.f;
  for (int i = s0; i < s1; ++i) {
    int e = csr[i];
    int src = ei[e];
    float mv = (float)xn[(size_t)src * DD + t] + eattr[(size_t)e * DD + t];
    acc += fmaxf(mv, 0.f);
  }
  float eps = epsp[0];
  hin[(size_t)n * DD + t] = (bf16)((1.f + eps) * (float)xn[(size_t)n * DD + t] + acc);
}

// ---------------- bf16 MFMA GEMM: C = A(MxK) @ W(NCxK)^T + bias, fused epilogues ----------------
// grid: (NC/64, ceil(M/64)); block 256 (4 waves); wave computes 16 rows x 64 cols.
__global__ __launch_bounds__(256) void gemm_bt(const bf16* __restrict__ A,
                                               const bf16* __restrict__ W,
                                               const float* __restrict__ bias,
                                               int M, int K, int NC, int mode,
                                               const float* __restrict__ res,
                                               const float* __restrict__ gamma,
                                               float* __restrict__ outf,
                                               bf16* __restrict__ outb) {
  int wave = threadIdx.x >> 6;
  int lane = threadIdx.x & 63;
  int qd = lane >> 4;
  int l16 = lane & 15;
  int r0 = blockIdx.y * 64 + wave * 16;
  int c0 = blockIdx.x * 64;
  int arow = r0 + l16;
  if (arow >= M) arow = M - 1;
  const bf16* Ap = A + (size_t)arow * K + qd * 8;
  const bf16* Wp = W + (size_t)(c0 + l16) * K + qd * 8;
  size_t K16 = (size_t)16 * K;
  f32x4 acc0 = {0.f, 0.f, 0.f, 0.f};
  f32x4 acc1 = acc0, acc2 = acc0, acc3 = acc0;
  for (int k = 0; k < K; k += 32) {
    bf16x8 a = *(const bf16x8*)(Ap + k);
    bf16x8 b0 = *(const bf16x8*)(Wp + k);
    bf16x8 b1 = *(const bf16x8*)(Wp + K16 + k);
    bf16x8 b2 = *(const bf16x8*)(Wp + 2 * K16 + k);
    bf16x8 b3 = *(const bf16x8*)(Wp + 3 * K16 + k);
    acc0 = __builtin_amdgcn_mfma_f32_16x16x32_bf16(a, b0, acc0, 0, 0, 0);
    acc1 = __builtin_amdgcn_mfma_f32_16x16x32_bf16(a, b1, acc1, 0, 0, 0);
    acc2 = __builtin_amdgcn_mfma_f32_16x16x32_bf16(a, b2, acc2, 0, 0, 0);
    acc3 = __builtin_amdgcn_mfma_f32_16x16x32_bf16(a, b3, acc3, 0, 0, 0);
  }
  f32x4 accs[4] = {acc0, acc1, acc2, acc3};
#pragma unroll
  for (int c = 0; c < 4; ++c) {
    int col = c0 + c * 16 + l16;
    float bv = bias[col];
#pragma unroll
    for (int i = 0; i < 4; ++i) {
      int row = r0 + qd * 4 + i;
      if (row >= M) continue;
      size_t idx = (size_t)row * NC + col;
      float v = accs[c][i] + bv;
      if (mode == GM_F32) outf[idx] = v;
      else if (mode == GM_BF16) outb[idx] = (bf16)v;
      else if (mode == GM_GELU) outb[idx] = (bf16)gelu_f(v);
      else {
        float g = gamma ? gamma[col] : 1.f;
        outf[idx] = res[idx] + g * v;
      }
    }
  }
}

// ---------------- batch segment sum (batch sorted) ----------------
__global__ __launch_bounds__(256) void cnt_kernel(const int* __restrict__ batch, float* __restrict__ cntf) {
  int n = blockIdx.x * 256 + threadIdx.x;
  if (n < NN) atomicAdd(&cntf[batch[n]], 1.f);
}

__global__ __launch_bounds__(256) void seg_sum(const float* __restrict__ x1,
                                               const int* __restrict__ batch,
                                               float* __restrict__ summary) {
  int r0 = blockIdx.x * 128;
  int t = threadIdx.x;
  float acc = 0.f;
  int curb = batch[r0];
  for (int i = 0; i < 128; ++i) {
    int r = r0 + i;
    int b = batch[r];
    if (b != curb) {
      atomicAdd(&summary[(size_t)curb * DD + t], acc);
      acc = 0.f;
      curb = b;
    }
    acc += x1[(size_t)r * DD + t];
  }
  atomicAdd(&summary[(size_t)curb * DD + t], acc);
}

// ctx = [vn (T rows per b), node_summary/cnt (1 row per b)] as bf16. grid = B*(T+1)
__global__ __launch_bounds__(256) void build_ctx(const float* __restrict__ summary,
                                                 const float* __restrict__ cntf,
                                                 const bf16* __restrict__ vn,
                                                 bf16* __restrict__ ctx) {
  int r = blockIdx.x, t = threadIdx.x;
  int b = r / (TT + 1), k = r % (TT + 1);
  float val;
  if (k < TT) val = (float)vn[((size_t)(b * TT + k)) * DD + t];
  else val = summary[(size_t)b * DD + t] / fmaxf(cntf[b], 1.f);
  ctx[(size_t)r * DD + t] = (bf16)val;
}

// ---------------- small MHA on v (B=8 blocks) ----------------
__global__ __launch_bounds__(256) void mha_small(const float* __restrict__ qh,
                                                 const float* __restrict__ kvh,
                                                 bf16* __restrict__ vatt) {
  int b = blockIdx.x;
  int h = threadIdx.x >> 5, qi = threadIdx.x & 31;
  const float scale = 0.17677669529663687f;
  float sc[TT + 1];
  float mx = -1e30f;
  const float* qp = qh + ((size_t)(b * TT + qi)) * DD + h * HDD;
#pragma unroll
  for (int k = 0; k < TT + 1; ++k) {
    const float* kp = kvh + ((size_t)(b * (TT + 1) + k)) * 512 + h * HDD;
    float s = 0.f;
#pragma unroll
    for (int d = 0; d < HDD; ++d) s += qp[d] * kp[d];
    s *= scale;
    sc[k] = s;
    mx = fmaxf(mx, s);
  }
  float sum = 0.f;
#pragma unroll
  for (int k = 0; k < TT + 1; ++k) {
    sc[k] = __expf(sc[k] - mx);
    sum += sc[k];
  }
  float inv = 1.f / sum;
#pragma unroll
  for (int d = 0; d < HDD; ++d) {
    float o = 0.f;
#pragma unroll
    for (int k = 0; k < TT + 1; ++k)
      o += sc[k] * kvh[((size_t)(b * (TT + 1) + k)) * 512 + 256 + h * HDD + d];
    vatt[((size_t)(b * TT + qi)) * DD + h * HDD + d] = (bf16)(o * inv);
  }
}

// ---------------- per-node cross attention (16 nodes per block) ----------------
__global__ __launch_bounds__(256) void cross_attn(const bf16* __restrict__ qx,
                                                  const float* __restrict__ kvx,
                                                  const int* __restrict__ batch,
                                                  bf16* __restrict__ attnout) {
  __shared__ float v_lds[TT * DD];  // 32 KB
  int tid = threadIdx.x;
  int n0 = blockIdx.x * 16;
  int b0 = batch[n0];
  for (int i = tid; i < TT * DD; i += 256) {
    int t = i >> 8, c = i & 255;
    v_lds[i] = kvx[((size_t)(b0 * TT + t)) * 512 + 256 + c];
  }
  int h = tid >> 5, lt = tid & 31;
  float kreg[HDD];
  {
    const float* kp = kvx + ((size_t)(b0 * TT + lt)) * 512 + h * HDD;
#pragma unroll
    for (int d = 0; d < HDD; ++d) kreg[d] = kp[d];
  }
  __syncthreads();
  const float scale = 0.17677669529663687f;
  for (int ni = 0; ni < 16; ++ni) {
    int n = n0 + ni;
    int b = batch[n];
    const bf16* qp = qx + (size_t)n * DD + h * HDD;
    float s = 0.f;
    if (b == b0) {
#pragma unroll
      for (int d = 0; d < HDD; ++d) s += (float)qp[d] * kreg[d];
    } else {
      const float* kp = kvx + ((size_t)(b * TT + lt)) * 512 + h * HDD;
#pragma unroll
      for (int d = 0; d < HDD; ++d) s += (float)qp[d] * kp[d];
    }
    s *= scale;
    float mx = s;
#pragma unroll
    for (int o = 16; o > 0; o >>= 1) mx = fmaxf(mx, __shfl_xor(mx, o, 32));
    float e = __expf(s - mx);
    float sum = e;
#pragma unroll
    for (int o = 16; o > 0; o >>= 1) sum += __shfl_xor(sum, o, 32);
    float a = e / sum;
    float o_acc = 0.f;
    int base_lane = (h & 1) << 5;
    if (b == b0) {
#pragma unroll
      for (int t = 0; t < TT; ++t) {
        float at = __shfl(a, base_lane + t, 64);
        o_acc += at * v_lds[t * DD + h * HDD + lt];
      }
    } else {
#pragma unroll
      for (int t = 0; t < TT; ++t) {
        float at = __shfl(a, base_lane + t, 64);
        o_acc += at * kvx[((size_t)(b * TT + t)) * 512 + 256 + h * HDD + lt];
      }
    }
    attnout[(size_t)n * DD + h * HDD + lt] = (bf16)o_acc;
  }
}

// ---------------- host launch ----------------
extern "C" void kernel_launch(void* const* d_in, const int* in_sizes, int n_in,
                              void* d_out, int out_size, void* d_ws, size_t ws_size,
                              hipStream_t stream) {
  const float* x = (const float*)d_in[0];
  const int* ei = (const int*)d_in[1];
  const float* eattr = (const float*)d_in[2];
  const float* v = (const float*)d_in[3];
  const int* batch = (const int*)d_in[4];
  const float* n1_g = (const float*)d_in[5];
  const float* n1_b = (const float*)d_in[6];
  const float* vn_g = (const float*)d_in[7];
  const float* vn_b = (const float*)d_in[8];
  const float* n3_g = (const float*)d_in[9];
  const float* n3_b = (const float*)d_in[10];
  const float* n4_g = (const float*)d_in[11];
  const float* n4_b = (const float*)d_in[12];
  const float* gine_eps = (const float*)d_in[13];
  const float* g_w1 = (const float*)d_in[14];
  const float* g_b1 = (const float*)d_in[15];
  const float* g_lng = (const float*)d_in[16];
  const float* g_lnb = (const float*)d_in[17];
  const float* g_w2 = (const float*)d_in[18];
  const float* g_b2 = (const float*)d_in[19];
  const float* gamma1 = (const float*)d_in[20];
  const float* gamma2 = (const float*)d_in[21];
  const float* gamma3 = (const float*)d_in[22];
  const float* mha_in_w = (const float*)d_in[23];
  const float* mha_in_b = (const float*)d_in[24];
  const float* mha_out_w = (const float*)d_in[25];
  const float* mha_out_b = (const float*)d_in[26];
  const float* q_w = (const float*)d_in[27];
  const float* q_b = (const float*)d_in[28];
  const float* kv_w = (const float*)d_in[29];
  const float* kv_b = (const float*)d_in[30];
  const float* o_w = (const float*)d_in[31];
  const float* o_b = (const float*)d_in[32];
  const float* f_w1 = (const float*)d_in[33];
  const float* f_b1 = (const float*)d_in[34];
  const float* f_w2 = (const float*)d_in[35];
  const float* f_b2 = (const float*)d_in[36];

  float* out_x = (float*)d_out;
  float* out_v = (float*)d_out + (size_t)NN * DD;

  char* wsp = (char*)d_ws;
  size_t off = 0;
  auto alloc = [&](size_t bytes) -> void* {
    void* p = wsp + off;
    off += (bytes + 255) & ~(size_t)255;
    return p;
  };
  // aliased arenas (lifetimes disjoint)
  float* t1f = (float*)alloc(33554432);  // S1: t1 f32 (N x 512) -> later u bf16 (N x 1024)
  bf16* u_bf = (bf16*)t1f;
  bf16* xn_bf = (bf16*)alloc(8388608);   // S2: xn -> later qx
  bf16* qx_bf = xn_bf;
  bf16* t1g_bf = (bf16*)alloc(16777216); // S3: t1g bf16 -> later x2 f32
  float* x2f = (float*)t1g_bf;
  float* x1f = (float*)alloc(16777216);  // S4
  bf16* hin_bf = (bf16*)alloc(8388608);  // S5: hin -> later xn3
  bf16* xn3_bf = hin_bf;
  bf16* att_bf = (bf16*)alloc(8388608);  // S6: attnout -> later xn4
  bf16* xn4_bf = att_bf;
  int* deg = (int*)alloc(NN * 4);
  int* psum = (int*)alloc(64 * 4);
  int* pbase = (int*)alloc(64 * 4);
  int* offs = (int*)alloc((NN + 1) * 4);
  int* woff = (int*)alloc(NN * 4);
  int* csr = (int*)alloc(EE * 4);
  float* summary = (float*)alloc(BB * DD * 4);
  float* cntf = (float*)alloc(BB * 4);
  bf16* vn_bf = (bf16*)alloc(BB * TT * DD * 2);
  bf16* ctx_bf = (bf16*)alloc(BB * (TT + 1) * DD * 2);
  float* qhf = (float*)alloc(BB * TT * DD * 4);
  float* kvhf = (float*)alloc(BB * (TT + 1) * 512 * 4);
  bf16* vatt_bf = (bf16*)alloc(BB * TT * DD * 2);
  bf16* vout_bf = (bf16*)alloc(BB * TT * DD * 2);
  float* kvxf = (float*)alloc(BB * TT * 512 * 4);
  bf16* wbuf = (bf16*)alloc((size_t)1310720 * 2);

  bf16* g_w1b = wbuf;
  bf16* g_w2b = g_w1b + 131072;
  bf16* mha_in_wb = g_w2b + 131072;
  bf16* mha_out_wb = mha_in_wb + 196608;
  bf16* q_wb = mha_out_wb + 65536;
  bf16* kv_wb = q_wb + 65536;
  bf16* o_wb = kv_wb + 131072;
  bf16* f_w1b = o_wb + 65536;
  bf16* f_w2b = f_w1b + 262144;

  // 0. cast all weights to bf16 in one launch
  Cast9 cj;
  cj.src[0] = g_w1; cj.dst[0] = g_w1b;
  cj.src[1] = g_w2; cj.dst[1] = g_w2b;
  cj.src[2] = mha_in_w; cj.dst[2] = mha_in_wb;
  cj.src[3] = mha_out_w; cj.dst[3] = mha_out_wb;
  cj.src[4] = q_w; cj.dst[4] = q_wb;
  cj.src[5] = kv_w; cj.dst[5] = kv_wb;
  cj.src[6] = o_w; cj.dst[6] = o_wb;
  cj.src[7] = f_w1; cj.dst[7] = f_w1b;
  cj.src[8] = f_w2; cj.dst[8] = f_w2b;
  int bs[10] = {0, 128, 256, 448, 512, 576, 704, 768, 1024, 1280};
  for (int i = 0; i < 10; ++i) cj.blk_start[i] = bs[i];
  cast9<<<1280, 256, 0, stream>>>(cj);

  // 1. xn = LN(x)
  ln_rows<<<NN, 256, 0, stream>>>(x, n1_g, n1_b, xn_bf, DD, 0);

  // 2. CSR by destination
  hipMemsetAsync(deg, 0, NN * 4, stream);
  deg_count<<<EE / 256, 256, 0, stream>>>(ei, deg);
  chunk_sum<<<64, 256, 0, stream>>>(deg, psum);
  scan_psum<<<1, 64, 0, stream>>>(psum, pbase);
  chunk_scan<<<64, 256, 0, stream>>>(deg, pbase, offs, woff);
  csr_fill<<<EE / 256, 256, 0, stream>>>(ei, woff, csr);

  // 3. GINE aggregation -> hin (bf16)
  gine_agg<<<NN, 256, 0, stream>>>(ei, eattr, xn_bf, offs, csr, gine_eps, hin_bf);

  // 4. GINE MLP: t1 = hin @ g_w1^T + g_b1 ; LN512+gelu ; x1 = x + gamma1*(t1g @ g_w2^T + g_b2)
  gemm_bt<<<dim3(8, 256), 256, 0, stream>>>(hin_bf, g_w1b, g_b1, NN, 256, 512, GM_F32,
                                            nullptr, nullptr, t1f, nullptr);
  ln_rows<<<NN, 256, 0, stream>>>(t1f, g_lng, g_lnb, t1g_bf, 512, 1);
  gemm_bt<<<dim3(4, 256), 256, 0, stream>>>(t1g_bf, g_w2b, g_b2, NN, 512, 256, GM_RES,
                                            x, gamma1, x1f, nullptr);

  // 5. node summary over batch
  hipMemsetAsync(summary, 0, BB * DD * 4, stream);
  hipMemsetAsync(cntf, 0, BB * 4, stream);
  cnt_kernel<<<NN / 256, 256, 0, stream>>>(batch, cntf);
  seg_sum<<<NN / 128, 256, 0, stream>>>(x1f, batch, summary);

  // 6. small MHA over v
  ln_rows<<<BB * TT, 256, 0, stream>>>(v, vn_g, vn_b, vn_bf, DD, 0);
  build_ctx<<<BB * (TT + 1), 256, 0, stream>>>(summary, cntf, vn_bf, ctx_bf);
  gemm_bt<<<dim3(4, 4), 256, 0, stream>>>(vn_bf, mha_in_wb, mha_in_b, BB * TT, 256, 256,
                                          GM_F32, nullptr, nullptr, qhf, nullptr);
  gemm_bt<<<dim3(8, 5), 256, 0, stream>>>(ctx_bf, mha_in_wb + (size_t)256 * 256,
                                          mha_in_b + 256, BB * (TT + 1), 256, 512,
                                          GM_F32, nullptr, nullptr, kvhf, nullptr);
  mha_small<<<BB, 256, 0, stream>>>(qhf, kvhf, vatt_bf);
  gemm_bt<<<dim3(4, 4), 256, 0, stream>>>(vatt_bf, mha_out_wb, mha_out_b, BB * TT, 256, 256,
                                          GM_RES, v, gamma2, out_v, nullptr);

  // 7. cross attention x <- v
  cast_f32_bf16_k<<<BB * TT * DD / 256, 256, 0, stream>>>(out_v, vout_bf, BB * TT * DD);
  gemm_bt<<<dim3(8, 4), 256, 0, stream>>>(vout_bf, kv_wb, kv_b, BB * TT, 256, 512,
                                          GM_F32, nullptr, nullptr, kvxf, nullptr);
  ln_rows<<<NN, 256, 0, stream>>>(x1f, n3_g, n3_b, xn3_bf, DD, 0);
  gemm_bt<<<dim3(4, 256), 256, 0, stream>>>(xn3_bf, q_wb, q_b, NN, 256, 256, GM_BF16,
                                            nullptr, nullptr, nullptr, qx_bf);
  cross_attn<<<NN / 16, 256, 0, stream>>>(qx_bf, kvxf, batch, att_bf);
  gemm_bt<<<dim3(4, 256), 256, 0, stream>>>(att_bf, o_wb, o_b, NN, 256, 256, GM_RES,
                                            x1f, gamma3, x2f, nullptr);

  // 8. FFN
  ln_rows<<<NN, 256, 0, stream>>>(x2f, n4_g, n4_b, xn4_bf, DD, 0);
  gemm_bt<<<dim3(16, 256), 256, 0, stream>>>(xn4_bf, f_w1b, f_b1, NN, 256, 1024, GM_GELU,
                                             nullptr, nullptr, nullptr, u_bf);
  gemm_bt<<<dim3(4, 256), 256, 0, stream>>>(u_bf, f_w2b, f_b2, NN, 1024, 256, GM_RES,
                                            x2f, nullptr, out_x, nullptr);
}

// Round 2
// 1086.848 us; speedup vs baseline: 1.1888x; 1.1888x over previous
//
#include <hip/hip_runtime.h>
#include <math.h>

#define NN 16384
#define EE 262144
#define BB 8
#define TT 32
#define DD 256
#define HH 8
#define HDD 32

typedef __bf16 bf16;
typedef __bf16 bf16x8 __attribute__((ext_vector_type(8)));
typedef __bf16 bf16x4 __attribute__((ext_vector_type(4)));
typedef float f32x4 __attribute__((ext_vector_type(4)));

#define GM_F32 0
#define GM_BF16 1
#define GM_GELU 2
#define GM_RES 3

__device__ __forceinline__ float gelu_f(float v) {
  return 0.5f * v * (1.f + erff(v * 0.70710678118654752440f));
}

// ---------------- weight cast (9 weights, one launch) ----------------
struct Cast9 {
  const float* src[9];
  bf16* dst[9];
  int blk_start[10];
};

__global__ __launch_bounds__(256) void cast9(Cast9 c) {
  int blk = blockIdx.x;
  int s = 0;
  while (blk >= c.blk_start[s + 1]) ++s;
  int local = blk - c.blk_start[s];
  int i = local * 1024 + threadIdx.x * 4;
  const float4 f = *(const float4*)(c.src[s] + i);
  bf16x4 o;
  o[0] = (bf16)f.x; o[1] = (bf16)f.y; o[2] = (bf16)f.z; o[3] = (bf16)f.w;
  *(bf16x4*)(c.dst[s] + i) = o;
}

__global__ __launch_bounds__(256) void cast_f32_bf16_k(const float* __restrict__ src,
                                                       bf16* __restrict__ dst, int n) {
  int i = blockIdx.x * 256 + threadIdx.x;
  if (i < n) dst[i] = (bf16)src[i];
}

// ---------------- rowwise LayerNorm (f32 in, bf16 out, optional gelu) ----------------
__global__ __launch_bounds__(256) void ln_rows(const float* __restrict__ in,
                                               const float* __restrict__ g,
                                               const float* __restrict__ b,
                                               bf16* __restrict__ out, int C, int do_gelu) {
  int row = blockIdx.x;
  const float* x = in + (size_t)row * C;
  float s = 0.f, s2 = 0.f;
  for (int c = threadIdx.x; c < C; c += 256) {
    float v = x[c];
    s += v;
    s2 += v * v;
  }
#pragma unroll
  for (int o = 32; o > 0; o >>= 1) {
    s += __shfl_down(s, o, 64);
    s2 += __shfl_down(s2, o, 64);
  }
  __shared__ float red[8];
  int wv = threadIdx.x >> 6;
  if ((threadIdx.x & 63) == 0) { red[wv] = s; red[4 + wv] = s2; }
  __syncthreads();
  s = red[0] + red[1] + red[2] + red[3];
  s2 = red[4] + red[5] + red[6] + red[7];
  float m = s / C;
  float rs = rsqrtf(s2 / C - m * m + 1e-5f);
  for (int c = threadIdx.x; c < C; c += 256) {
    float v = (x[c] - m) * rs * g[c] + b[c];
    if (do_gelu) v = gelu_f(v);
    out[(size_t)row * C + c] = (bf16)v;
  }
}

// ---------------- CSR build ----------------
__global__ __launch_bounds__(256) void deg_count(const int* __restrict__ ei, int* __restrict__ deg) {
  int e = blockIdx.x * 256 + threadIdx.x;
  if (e < EE) atomicAdd(&deg[ei[EE + e]], 1);
}

__global__ __launch_bounds__(256) void chunk_sum(const int* __restrict__ deg, int* __restrict__ psum) {
  __shared__ int sh[256];
  sh[threadIdx.x] = deg[blockIdx.x * 256 + threadIdx.x];
  __syncthreads();
  for (int o = 128; o > 0; o >>= 1) {
    if (threadIdx.x < o) sh[threadIdx.x] += sh[threadIdx.x + o];
    __syncthreads();
  }
  if (threadIdx.x == 0) psum[blockIdx.x] = sh[0];
}

__global__ void scan_psum(const int* __restrict__ psum, int* __restrict__ pbase) {
  if (threadIdx.x == 0) {
    int acc = 0;
    for (int i = 0; i < 64; ++i) { pbase[i] = acc; acc += psum[i]; }
  }
}

__global__ __launch_bounds__(256) void chunk_scan(const int* __restrict__ deg,
                                                  const int* __restrict__ pbase,
                                                  int* __restrict__ offs, int* __restrict__ woff) {
  __shared__ int sh[256];
  int gi = blockIdx.x * 256 + threadIdx.x;
  int v = deg[gi];
  sh[threadIdx.x] = v;
  __syncthreads();
  for (int o = 1; o < 256; o <<= 1) {
    int t = (threadIdx.x >= o) ? sh[threadIdx.x - o] : 0;
    __syncthreads();
    sh[threadIdx.x] += t;
    __syncthreads();
  }
  int excl = pbase[blockIdx.x] + sh[threadIdx.x] - v;
  offs[gi] = excl;
  woff[gi] = excl;
  if (blockIdx.x == 63 && threadIdx.x == 255) offs[NN] = pbase[63] + sh[255];
}

__global__ __launch_bounds__(256) void csr_fill(const int* __restrict__ ei, int* __restrict__ woff,
                                                int* __restrict__ csr) {
  int e = blockIdx.x * 256 + threadIdx.x;
  if (e < EE) {
    int d = ei[EE + e];
    int p = atomicAdd(&woff[d], 1);
    csr[p] = e;
  }
}

// GINE aggregation: block per node, thread per channel. hin = (1+eps)*xn + sum relu(xn[src]+ea)
__global__ __launch_bounds__(256) void gine_agg(const int* __restrict__ ei,
                                                const float* __restrict__ eattr,
                                                const bf16* __restrict__ xn,
                                                const int* __restrict__ offs,
                                                const int* __restrict__ csr,
                                                const float* __restrict__ epsp,
                                                bf16* __restrict__ hin) {
  int n = blockIdx.x, t = threadIdx.x;
  int s0 = offs[n], s1 = offs[n + 1];
  float acc = 0.f;
  for (int i = s0; i < s1; ++i) {
    int e = csr[i];
    int src = ei[e];
    float mv = (float)xn[(size_t)src * DD + t] + eattr[(size_t)e * DD + t];
    acc += fmaxf(mv, 0.f);
  }
  float eps = epsp[0];
  hin[(size_t)n * DD + t] = (bf16)((1.f + eps) * (float)xn[(size_t)n * DD + t] + acc);
}

// ---------------- bf16 MFMA GEMM: C = A(MxK) @ W(NCxK)^T + bias, fused epilogues ----------------
// grid: (NC/64, ceil(M/64)); block 256 (4 waves); wave computes 16 rows x 64 cols.
__global__ __launch_bounds__(256) void gemm_bt(const bf16* __restrict__ A,
                                               const bf16* __restrict__ W,
                                               const float* __restrict__ bias,
                                               int M, int K, int NC, int mode,
                                               const float* __restrict__ res,
                                               const float* __restrict__ gamma,
                                               float* __restrict__ outf,
                                               bf16* __restrict__ outb) {
  int wave = threadIdx.x >> 6;
  int lane = threadIdx.x & 63;
  int qd = lane >> 4;
  int l16 = lane & 15;
  int r0 = blockIdx.y * 64 + wave * 16;
  int c0 = blockIdx.x * 64;
  int arow = r0 + l16;
  if (arow >= M) arow = M - 1;
  const bf16* Ap = A + (size_t)arow * K + qd * 8;
  const bf16* Wp = W + (size_t)(c0 + l16) * K + qd * 8;
  size_t K16 = (size_t)16 * K;
  f32x4 acc0 = {0.f, 0.f, 0.f, 0.f};
  f32x4 acc1 = acc0, acc2 = acc0, acc3 = acc0;
  for (int k = 0; k < K; k += 32) {
    bf16x8 a = *(const bf16x8*)(Ap + k);
    bf16x8 b0 = *(const bf16x8*)(Wp + k);
    bf16x8 b1 = *(const bf16x8*)(Wp + K16 + k);
    bf16x8 b2 = *(const bf16x8*)(Wp + 2 * K16 + k);
    bf16x8 b3 = *(const bf16x8*)(Wp + 3 * K16 + k);
    acc0 = __builtin_amdgcn_mfma_f32_16x16x32_bf16(a, b0, acc0, 0, 0, 0);
    acc1 = __builtin_amdgcn_mfma_f32_16x16x32_bf16(a, b1, acc1, 0, 0, 0);
    acc2 = __builtin_amdgcn_mfma_f32_16x16x32_bf16(a, b2, acc2, 0, 0, 0);
    acc3 = __builtin_amdgcn_mfma_f32_16x16x32_bf16(a, b3, acc3, 0, 0, 0);
  }
  f32x4 accs[4] = {acc0, acc1, acc2, acc3};
#pragma unroll
  for (int c = 0; c < 4; ++c) {
    int col = c0 + c * 16 + l16;
    float bv = bias[col];
#pragma unroll
    for (int i = 0; i < 4; ++i) {
      int row = r0 + qd * 4 + i;
      if (row >= M) continue;
      size_t idx = (size_t)row * NC + col;
      float v = accs[c][i] + bv;
      if (mode == GM_F32) outf[idx] = v;
      else if (mode == GM_BF16) outb[idx] = (bf16)v;
      else if (mode == GM_GELU) outb[idx] = (bf16)gelu_f(v);
      else {
        float g = gamma ? gamma[col] : 1.f;
        outf[idx] = res[idx] + g * v;
      }
    }
  }
}

// ---------------- batch count: LDS histogram, 8 global atomics per block ----------------
__global__ __launch_bounds__(256) void cnt_kernel(const int* __restrict__ batch, float* __restrict__ cntf) {
  __shared__ int hist[BB];
  if (threadIdx.x < BB) hist[threadIdx.x] = 0;
  __syncthreads();
  int n = blockIdx.x * 256 + threadIdx.x;
  if (n < NN) atomicAdd(&hist[batch[n]], 1);
  __syncthreads();
  if (threadIdx.x < BB) {
    int h = hist[threadIdx.x];
    if (h) atomicAdd(&cntf[threadIdx.x], (float)h);
  }
}

__global__ __launch_bounds__(256) void seg_sum(const float* __restrict__ x1,
                                               const int* __restrict__ batch,
                                               float* __restrict__ summary) {
  int r0 = blockIdx.x * 128;
  int t = threadIdx.x;
  float acc = 0.f;
  int curb = batch[r0];
  for (int i = 0; i < 128; ++i) {
    int r = r0 + i;
    int b = batch[r];
    if (b != curb) {
      atomicAdd(&summary[(size_t)curb * DD + t], acc);
      acc = 0.f;
      curb = b;
    }
    acc += x1[(size_t)r * DD + t];
  }
  atomicAdd(&summary[(size_t)curb * DD + t], acc);
}

// ctx = [vn (T rows per b), node_summary/cnt (1 row per b)] as bf16. grid = B*(T+1)
__global__ __launch_bounds__(256) void build_ctx(const float* __restrict__ summary,
                                                 const float* __restrict__ cntf,
                                                 const bf16* __restrict__ vn,
                                                 bf16* __restrict__ ctx) {
  int r = blockIdx.x, t = threadIdx.x;
  int b = r / (TT + 1), k = r % (TT + 1);
  float val;
  if (k < TT) val = (float)vn[((size_t)(b * TT + k)) * DD + t];
  else val = summary[(size_t)b * DD + t] / fmaxf(cntf[b], 1.f);
  ctx[(size_t)r * DD + t] = (bf16)val;
}

// ---------------- small MHA on v (B=8 blocks) ----------------
__global__ __launch_bounds__(256) void mha_small(const float* __restrict__ qh,
                                                 const float* __restrict__ kvh,
                                                 bf16* __restrict__ vatt) {
  int b = blockIdx.x;
  int h = threadIdx.x >> 5, qi = threadIdx.x & 31;
  const float scale = 0.17677669529663687f;
  float sc[TT + 1];
  float mx = -1e30f;
  const float* qp = qh + ((size_t)(b * TT + qi)) * DD + h * HDD;
#pragma unroll
  for (int k = 0; k < TT + 1; ++k) {
    const float* kp = kvh + ((size_t)(b * (TT + 1) + k)) * 512 + h * HDD;
    float s = 0.f;
#pragma unroll
    for (int d = 0; d < HDD; ++d) s += qp[d] * kp[d];
    s *= scale;
    sc[k] = s;
    mx = fmaxf(mx, s);
  }
  float sum = 0.f;
#pragma unroll
  for (int k = 0; k < TT + 1; ++k) {
    sc[k] = __expf(sc[k] - mx);
    sum += sc[k];
  }
  float inv = 1.f / sum;
#pragma unroll
  for (int d = 0; d < HDD; ++d) {
    float o = 0.f;
#pragma unroll
    for (int k = 0; k < TT + 1; ++k)
      o += sc[k] * kvh[((size_t)(b * (TT + 1) + k)) * 512 + 256 + h * HDD + d];
    vatt[((size_t)(b * TT + qi)) * DD + h * HDD + d] = (bf16)(o * inv);
  }
}

// ---------------- per-node cross attention (16 nodes per block) ----------------
__global__ __launch_bounds__(256) void cross_attn(const bf16* __restrict__ qx,
                                                  const float* __restrict__ kvx,
                                                  const int* __restrict__ batch,
                                                  bf16* __restrict__ attnout) {
  __shared__ float v_lds[TT * DD];  // 32 KB
  int tid = threadIdx.x;
  int n0 = blockIdx.x * 16;
  int b0 = batch[n0];
  for (int i = tid; i < TT * DD; i += 256) {
    int t = i >> 8, c = i & 255;
    v_lds[i] = kvx[((size_t)(b0 * TT + t)) * 512 + 256 + c];
  }
  int h = tid >> 5, lt = tid & 31;
  float kreg[HDD];
  {
    const float* kp = kvx + ((size_t)(b0 * TT + lt)) * 512 + h * HDD;
#pragma unroll
    for (int d = 0; d < HDD; ++d) kreg[d] = kp[d];
  }
  __syncthreads();
  const float scale = 0.17677669529663687f;
  for (int ni = 0; ni < 16; ++ni) {
    int n = n0 + ni;
    int b = batch[n];
    const bf16* qp = qx + (size_t)n * DD + h * HDD;
    float s = 0.f;
    if (b == b0) {
#pragma unroll
      for (int d = 0; d < HDD; ++d) s += (float)qp[d] * kreg[d];
    } else {
      const float* kp = kvx + ((size_t)(b * TT + lt)) * 512 + h * HDD;
#pragma unroll
      for (int d = 0; d < HDD; ++d) s += (float)qp[d] * kp[d];
    }
    s *= scale;
    float mx = s;
#pragma unroll
    for (int o = 16; o > 0; o >>= 1) mx = fmaxf(mx, __shfl_xor(mx, o, 32));
    float e = __expf(s - mx);
    float sum = e;
#pragma unroll
    for (int o = 16; o > 0; o >>= 1) sum += __shfl_xor(sum, o, 32);
    float a = e / sum;
    float o_acc = 0.f;
    int base_lane = (h & 1) << 5;
    if (b == b0) {
#pragma unroll
      for (int t = 0; t < TT; ++t) {
        float at = __shfl(a, base_lane + t, 64);
        o_acc += at * v_lds[t * DD + h * HDD + lt];
      }
    } else {
#pragma unroll
      for (int t = 0; t < TT; ++t) {
        float at = __shfl(a, base_lane + t, 64);
        o_acc += at * kvx[((size_t)(b * TT + t)) * 512 + 256 + h * HDD + lt];
      }
    }
    attnout[(size_t)n * DD + h * HDD + lt] = (bf16)o_acc;
  }
}

// ---------------- host launch ----------------
extern "C" void kernel_launch(void* const* d_in, const int* in_sizes, int n_in,
                              void* d_out, int out_size, void* d_ws, size_t ws_size,
                              hipStream_t stream) {
  const float* x = (const float*)d_in[0];
  const int* ei = (const int*)d_in[1];
  const float* eattr = (const float*)d_in[2];
  const float* v = (const float*)d_in[3];
  const int* batch = (const int*)d_in[4];
  const float* n1_g = (const float*)d_in[5];
  const float* n1_b = (const float*)d_in[6];
  const float* vn_g = (const float*)d_in[7];
  const float* vn_b = (const float*)d_in[8];
  const float* n3_g = (const float*)d_in[9];
  const float* n3_b = (const float*)d_in[10];
  const float* n4_g = (const float*)d_in[11];
  const float* n4_b = (const float*)d_in[12];
  const float* gine_eps = (const float*)d_in[13];
  const float* g_w1 = (const float*)d_in[14];
  const float* g_b1 = (const float*)d_in[15];
  const float* g_lng = (const float*)d_in[16];
  const float* g_lnb = (const float*)d_in[17];
  const float* g_w2 = (const float*)d_in[18];
  const float* g_b2 = (const float*)d_in[19];
  const float* gamma1 = (const float*)d_in[20];
  const float* gamma2 = (const float*)d_in[21];
  const float* gamma3 = (const float*)d_in[22];
  const float* mha_in_w = (const float*)d_in[23];
  const float* mha_in_b = (const float*)d_in[24];
  const float* mha_out_w = (const float*)d_in[25];
  const float* mha_out_b = (const float*)d_in[26];
  const float* q_w = (const float*)d_in[27];
  const float* q_b = (const float*)d_in[28];
  const float* kv_w = (const float*)d_in[29];
  const float* kv_b = (const float*)d_in[30];
  const float* o_w = (const float*)d_in[31];
  const float* o_b = (const float*)d_in[32];
  const float* f_w1 = (const float*)d_in[33];
  const float* f_b1 = (const float*)d_in[34];
  const float* f_w2 = (const float*)d_in[35];
  const float* f_b2 = (const float*)d_in[36];

  float* out_x = (float*)d_out;
  float* out_v = (float*)d_out + (size_t)NN * DD;

  char* wsp = (char*)d_ws;
  size_t off = 0;
  auto alloc = [&](size_t bytes) -> void* {
    void* p = wsp + off;
    off += (bytes + 255) & ~(size_t)255;
    return p;
  };
  // aliased arenas (lifetimes disjoint)
  float* t1f = (float*)alloc(33554432);  // S1: t1 f32 (N x 512) -> later u bf16 (N x 1024)
  bf16* u_bf = (bf16*)t1f;
  bf16* xn_bf = (bf16*)alloc(8388608);   // S2: xn -> later qx
  bf16* qx_bf = xn_bf;
  bf16* t1g_bf = (bf16*)alloc(16777216); // S3: t1g bf16 -> later x2 f32
  float* x2f = (float*)t1g_bf;
  float* x1f = (float*)alloc(16777216);  // S4
  bf16* hin_bf = (bf16*)alloc(8388608);  // S5: hin -> later xn3
  bf16* xn3_bf = hin_bf;
  bf16* att_bf = (bf16*)alloc(8388608);  // S6: attnout -> later xn4
  bf16* xn4_bf = att_bf;
  int* deg = (int*)alloc(NN * 4);
  int* psum = (int*)alloc(64 * 4);
  int* pbase = (int*)alloc(64 * 4);
  int* offs = (int*)alloc((NN + 1) * 4);
  int* woff = (int*)alloc(NN * 4);
  int* csr = (int*)alloc(EE * 4);
  float* summary = (float*)alloc(BB * DD * 4);
  float* cntf = (float*)alloc(BB * 4);
  bf16* vn_bf = (bf16*)alloc(BB * TT * DD * 2);
  bf16* ctx_bf = (bf16*)alloc(BB * (TT + 1) * DD * 2);
  float* qhf = (float*)alloc(BB * TT * DD * 4);
  float* kvhf = (float*)alloc(BB * (TT + 1) * 512 * 4);
  bf16* vatt_bf = (bf16*)alloc(BB * TT * DD * 2);
  bf16* vout_bf = (bf16*)alloc(BB * TT * DD * 2);
  float* kvxf = (float*)alloc(BB * TT * 512 * 4);
  bf16* wbuf = (bf16*)alloc((size_t)1310720 * 2);

  bf16* g_w1b = wbuf;
  bf16* g_w2b = g_w1b + 131072;
  bf16* mha_in_wb = g_w2b + 131072;
  bf16* mha_out_wb = mha_in_wb + 196608;
  bf16* q_wb = mha_out_wb + 65536;
  bf16* kv_wb = q_wb + 65536;
  bf16* o_wb = kv_wb + 131072;
  bf16* f_w1b = o_wb + 65536;
  bf16* f_w2b = f_w1b + 262144;

  // 0. cast all weights to bf16 in one launch
  Cast9 cj;
  cj.src[0] = g_w1; cj.dst[0] = g_w1b;
  cj.src[1] = g_w2; cj.dst[1] = g_w2b;
  cj.src[2] = mha_in_w; cj.dst[2] = mha_in_wb;
  cj.src[3] = mha_out_w; cj.dst[3] = mha_out_wb;
  cj.src[4] = q_w; cj.dst[4] = q_wb;
  cj.src[5] = kv_w; cj.dst[5] = kv_wb;
  cj.src[6] = o_w; cj.dst[6] = o_wb;
  cj.src[7] = f_w1; cj.dst[7] = f_w1b;
  cj.src[8] = f_w2; cj.dst[8] = f_w2b;
  int bs[10] = {0, 128, 256, 448, 512, 576, 704, 768, 1024, 1280};
  for (int i = 0; i < 10; ++i) cj.blk_start[i] = bs[i];
  cast9<<<1280, 256, 0, stream>>>(cj);

  // 1. xn = LN(x)
  ln_rows<<<NN, 256, 0, stream>>>(x, n1_g, n1_b, xn_bf, DD, 0);

  // 2. CSR by destination
  hipMemsetAsync(deg, 0, NN * 4, stream);
  deg_count<<<EE / 256, 256, 0, stream>>>(ei, deg);
  chunk_sum<<<64, 256, 0, stream>>>(deg, psum);
  scan_psum<<<1, 64, 0, stream>>>(psum, pbase);
  chunk_scan<<<64, 256, 0, stream>>>(deg, pbase, offs, woff);
  csr_fill<<<EE / 256, 256, 0, stream>>>(ei, woff, csr);

  // 3. GINE aggregation -> hin (bf16)
  gine_agg<<<NN, 256, 0, stream>>>(ei, eattr, xn_bf, offs, csr, gine_eps, hin_bf);

  // 4. GINE MLP: t1 = hin @ g_w1^T + g_b1 ; LN512+gelu ; x1 = x + gamma1*(t1g @ g_w2^T + g_b2)
  gemm_bt<<<dim3(8, 256), 256, 0, stream>>>(hin_bf, g_w1b, g_b1, NN, 256, 512, GM_F32,
                                            nullptr, nullptr, t1f, nullptr);
  ln_rows<<<NN, 256, 0, stream>>>(t1f, g_lng, g_lnb, t1g_bf, 512, 1);
  gemm_bt<<<dim3(4, 256), 256, 0, stream>>>(t1g_bf, g_w2b, g_b2, NN, 512, 256, GM_RES,
                                            x, gamma1, x1f, nullptr);

  // 5. node summary over batch
  hipMemsetAsync(summary, 0, BB * DD * 4, stream);
  hipMemsetAsync(cntf, 0, BB * 4, stream);
  cnt_kernel<<<NN / 256, 256, 0, stream>>>(batch, cntf);
  seg_sum<<<NN / 128, 256, 0, stream>>>(x1f, batch, summary);

  // 6. small MHA over v
  ln_rows<<<BB * TT, 256, 0, stream>>>(v, vn_g, vn_b, vn_bf, DD, 0);
  build_ctx<<<BB * (TT + 1), 256, 0, stream>>>(summary, cntf, vn_bf, ctx_bf);
  gemm_bt<<<dim3(4, 4), 256, 0, stream>>>(vn_bf, mha_in_wb, mha_in_b, BB * TT, 256, 256,
                                          GM_F32, nullptr, nullptr, qhf, nullptr);
  gemm_bt<<<dim3(8, 5), 256, 0, stream>>>(ctx_bf, mha_in_wb + (size_t)256 * 256,
                                          mha_in_b + 256, BB * (TT + 1), 256, 512,
                                          GM_F32, nullptr, nullptr, kvhf, nullptr);
  mha_small<<<BB, 256, 0, stream>>>(qhf, kvhf, vatt_bf);
  gemm_bt<<<dim3(4, 4), 256, 0, stream>>>(vatt_bf, mha_out_wb, mha_out_b, BB * TT, 256, 256,
                                          GM_RES, v, gamma2, out_v, nullptr);

  // 7. cross attention x <- v
  cast_f32_bf16_k<<<BB * TT * DD / 256, 256, 0, stream>>>(out_v, vout_bf, BB * TT * DD);
  gemm_bt<<<dim3(8, 4), 256, 0, stream>>>(vout_bf, kv_wb, kv_b, BB * TT, 256, 512,
                                          GM_F32, nullptr, nullptr, kvxf, nullptr);
  ln_rows<<<NN, 256, 0, stream>>>(x1f, n3_g, n3_b, xn3_bf, DD, 0);
  gemm_bt<<<dim3(4, 256), 256, 0, stream>>>(xn3_bf, q_wb, q_b, NN, 256, 256, GM_BF16,
                                            nullptr, nullptr, nullptr, qx_bf);
  cross_attn<<<NN / 16, 256, 0, stream>>>(qx_bf, kvxf, batch, att_bf);
  gemm_bt<<<dim3(4, 256), 256, 0, stream>>>(att_bf, o_wb, o_b, NN, 256, 256, GM_RES,
                                            x1f, gamma3, x2f, nullptr);

  // 8. FFN
  ln_rows<<<NN, 256, 0, stream>>>(x2f, n4_g, n4_b, xn4_bf, DD, 0);
  gemm_bt<<<dim3(16, 256), 256, 0, stream>>>(xn4_bf, f_w1b, f_b1, NN, 256, 1024, GM_GELU,
                                             nullptr, nullptr, nullptr, u_bf);
  gemm_bt<<<dim3(4, 256), 256, 0, stream>>>(u_bf, f_w2b, f_b2, NN, 1024, 256, GM_RES,
                                            x2f, nullptr, out_x, nullptr);
}

// Round 3
// 959.720 us; speedup vs baseline: 1.3463x; 1.1325x over previous
//
#include <hip/hip_runtime.h>
#include <math.h>

#define NN 16384
#define EE 262144
#define BB 8
#define TT 32
#define DD 256
#define HH 8
#define HDD 32

typedef __bf16 bf16;
typedef __bf16 bf16x8 __attribute__((ext_vector_type(8)));
typedef __bf16 bf16x4 __attribute__((ext_vector_type(4)));
typedef float f32x4 __attribute__((ext_vector_type(4)));

#define GM_F32 0
#define GM_BF16 1
#define GM_GELU 2
#define GM_RES 3
#define GM_RES2 4

__device__ __forceinline__ float gelu_f(float v) {
  return 0.5f * v * (1.f + erff(v * 0.70710678118654752440f));
}

// ---------------- weight cast (9 weights, one launch) ----------------
struct Cast9 {
  const float* src[9];
  bf16* dst[9];
  int blk_start[10];
};

__global__ __launch_bounds__(256) void cast9(Cast9 c) {
  int blk = blockIdx.x;
  int s = 0;
  while (blk >= c.blk_start[s + 1]) ++s;
  int local = blk - c.blk_start[s];
  int i = local * 1024 + threadIdx.x * 4;
  const float4 f = *(const float4*)(c.src[s] + i);
  bf16x4 o;
  o[0] = (bf16)f.x; o[1] = (bf16)f.y; o[2] = (bf16)f.z; o[3] = (bf16)f.w;
  *(bf16x4*)(c.dst[s] + i) = o;
}

// ---------------- zero scratch (replaces 3 memsets) ----------------
__global__ __launch_bounds__(256) void zero_bufs(int* __restrict__ deg,
                                                 float* __restrict__ summary,
                                                 float* __restrict__ cntf) {
  int b = blockIdx.x;
  if (b < 64) deg[b * 256 + threadIdx.x] = 0;
  else if (b < 72) summary[(b - 64) * 256 + threadIdx.x] = 0.f;
  else if (threadIdx.x < BB) cntf[threadIdx.x] = 0.f;
}

// ---------------- rowwise LayerNorm, single pass (f32 in, bf16 out, optional gelu) ----------------
__global__ __launch_bounds__(256) void ln_rows(const float* __restrict__ in,
                                               const float* __restrict__ g,
                                               const float* __restrict__ b,
                                               bf16* __restrict__ out, int C, int do_gelu) {
  int row = blockIdx.x;
  int t = threadIdx.x;
  const float* x = in + (size_t)row * C;
  int nc = C >> 8;  // 1 or 2
  float lv[2];
  float s = 0.f, s2 = 0.f;
  for (int j = 0; j < nc; ++j) {
    float v = x[j * 256 + t];
    lv[j] = v;
    s += v;
    s2 += v * v;
  }
#pragma unroll
  for (int o = 32; o > 0; o >>= 1) {
    s += __shfl_down(s, o, 64);
    s2 += __shfl_down(s2, o, 64);
  }
  __shared__ float red[8];
  int wv = t >> 6;
  if ((t & 63) == 0) { red[wv] = s; red[4 + wv] = s2; }
  __syncthreads();
  s = red[0] + red[1] + red[2] + red[3];
  s2 = red[4] + red[5] + red[6] + red[7];
  float m = s / C;
  float rs = rsqrtf(s2 / C - m * m + 1e-5f);
  for (int j = 0; j < nc; ++j) {
    int c = j * 256 + t;
    float v = (lv[j] - m) * rs * g[c] + b[c];
    if (do_gelu) v = gelu_f(v);
    out[(size_t)row * C + c] = (bf16)v;
  }
}

// ---------------- CSR build ----------------
__global__ __launch_bounds__(256) void deg_count(const int* __restrict__ ei, int* __restrict__ deg) {
  int e = blockIdx.x * 256 + threadIdx.x;
  if (e < EE) atomicAdd(&deg[ei[EE + e]], 1);
}

// one-block full scan of the 16384 degrees
__global__ __launch_bounds__(1024) void scan16k(const int* __restrict__ deg,
                                                int* __restrict__ offs, int* __restrict__ woff) {
  __shared__ int part[1024];
  int t = threadIdx.x;
  int base = t * 16;
  int v[16];
  int s = 0;
#pragma unroll
  for (int j = 0; j < 16; ++j) { v[j] = deg[base + j]; s += v[j]; }
  part[t] = s;
  __syncthreads();
  for (int o = 1; o < 1024; o <<= 1) {
    int x = (t >= o) ? part[t - o] : 0;
    __syncthreads();
    part[t] += x;
    __syncthreads();
  }
  int excl = part[t] - s;
#pragma unroll
  for (int j = 0; j < 16; ++j) {
    offs[base + j] = excl;
    woff[base + j] = excl;
    excl += v[j];
  }
  if (t == 1023) offs[NN] = part[1023];
}

// packed (edge, src) CSR fill
__global__ __launch_bounds__(256) void csr_fill(const int* __restrict__ ei, int* __restrict__ woff,
                                                int2* __restrict__ csr2) {
  int e = blockIdx.x * 256 + threadIdx.x;
  if (e < EE) {
    int d = ei[EE + e];
    int s = ei[e];
    int p = atomicAdd(&woff[d], 1);
    csr2[p] = make_int2(e, s);
  }
}

// GINE aggregation: block per node, wave per edge (4 in flight), lane covers 4 channels.
__global__ __launch_bounds__(256) void gine_agg(const float* __restrict__ eattr,
                                                const bf16* __restrict__ xn,
                                                const int* __restrict__ offs,
                                                const int2* __restrict__ csr2,
                                                const float* __restrict__ epsp,
                                                bf16* __restrict__ hin) {
  __shared__ f32x4 red[4][64];
  int n = blockIdx.x;
  int wave = threadIdx.x >> 6, lane = threadIdx.x & 63;
  int s0 = offs[n], s1 = offs[n + 1];
  f32x4 acc = {0.f, 0.f, 0.f, 0.f};
  int i = s0 + wave;
  int2 es = (i < s1) ? csr2[i] : make_int2(0, 0);
  for (; i < s1; i += 4) {
    int2 cur = es;
    int inext = i + 4;
    if (inext < s1) es = csr2[inext];
    float4 ea = *(const float4*)(eattr + (size_t)cur.x * DD + lane * 4);
    bf16x4 xv = *(const bf16x4*)(xn + (size_t)cur.y * DD + lane * 4);
    acc[0] += fmaxf((float)xv[0] + ea.x, 0.f);
    acc[1] += fmaxf((float)xv[1] + ea.y, 0.f);
    acc[2] += fmaxf((float)xv[2] + ea.z, 0.f);
    acc[3] += fmaxf((float)xv[3] + ea.w, 0.f);
  }
  red[wave][lane] = acc;
  __syncthreads();
  if (wave == 0) {
    f32x4 a = red[0][lane];
    f32x4 a1 = red[1][lane], a2 = red[2][lane], a3 = red[3][lane];
    bf16x4 xs = *(const bf16x4*)(xn + (size_t)n * DD + lane * 4);
    float e1 = 1.f + epsp[0];
    bf16x4 o;
#pragma unroll
    for (int j = 0; j < 4; ++j)
      o[j] = (bf16)(e1 * (float)xs[j] + a[j] + a1[j] + a2[j] + a3[j]);
    *(bf16x4*)(hin + (size_t)n * DD + lane * 4) = o;
  }
}

// ---------------- bf16 MFMA GEMM: C = A(MxK) @ W(NCxK)^T + bias, fused epilogues ----------------
// grid: (NC/64, ceil(M/128)); block 256 (4 waves); wave computes 32 rows x 64 cols.
__global__ __launch_bounds__(256) void gemm_bt(const bf16* __restrict__ A,
                                               const bf16* __restrict__ W,
                                               const float* __restrict__ bias,
                                               int M, int K, int NC, int mode,
                                               const float* __restrict__ res,
                                               const float* __restrict__ gamma,
                                               float* __restrict__ outf,
                                               bf16* __restrict__ outb) {
  int wave = threadIdx.x >> 6;
  int lane = threadIdx.x & 63;
  int qd = lane >> 4;
  int l16 = lane & 15;
  int r0 = blockIdx.y * 128 + wave * 32;
  int c0 = blockIdx.x * 64;
  int ar0 = r0 + l16;       if (ar0 >= M) ar0 = M - 1;
  int ar1 = r0 + 16 + l16;  if (ar1 >= M) ar1 = M - 1;
  const bf16* Ap0 = A + (size_t)ar0 * K + qd * 8;
  const bf16* Ap1 = A + (size_t)ar1 * K + qd * 8;
  const bf16* Wp = W + (size_t)(c0 + l16) * K + qd * 8;
  size_t K16 = (size_t)16 * K;
  f32x4 acc00 = {0.f, 0.f, 0.f, 0.f};
  f32x4 acc01 = acc00, acc02 = acc00, acc03 = acc00;
  f32x4 acc10 = acc00, acc11 = acc00, acc12 = acc00, acc13 = acc00;
  for (int k = 0; k < K; k += 32) {
    bf16x8 a0 = *(const bf16x8*)(Ap0 + k);
    bf16x8 a1 = *(const bf16x8*)(Ap1 + k);
    bf16x8 b0 = *(const bf16x8*)(Wp + k);
    bf16x8 b1 = *(const bf16x8*)(Wp + K16 + k);
    bf16x8 b2 = *(const bf16x8*)(Wp + 2 * K16 + k);
    bf16x8 b3 = *(const bf16x8*)(Wp + 3 * K16 + k);
    acc00 = __builtin_amdgcn_mfma_f32_16x16x32_bf16(a0, b0, acc00, 0, 0, 0);
    acc01 = __builtin_amdgcn_mfma_f32_16x16x32_bf16(a0, b1, acc01, 0, 0, 0);
    acc02 = __builtin_amdgcn_mfma_f32_16x16x32_bf16(a0, b2, acc02, 0, 0, 0);
    acc03 = __builtin_amdgcn_mfma_f32_16x16x32_bf16(a0, b3, acc03, 0, 0, 0);
    acc10 = __builtin_amdgcn_mfma_f32_16x16x32_bf16(a1, b0, acc10, 0, 0, 0);
    acc11 = __builtin_amdgcn_mfma_f32_16x16x32_bf16(a1, b1, acc11, 0, 0, 0);
    acc12 = __builtin_amdgcn_mfma_f32_16x16x32_bf16(a1, b2, acc12, 0, 0, 0);
    acc13 = __builtin_amdgcn_mfma_f32_16x16x32_bf16(a1, b3, acc13, 0, 0, 0);
  }
  f32x4 accs[2][4] = {{acc00, acc01, acc02, acc03}, {acc10, acc11, acc12, acc13}};
#pragma unroll
  for (int s = 0; s < 2; ++s) {
#pragma unroll
    for (int c = 0; c < 4; ++c) {
      int col = c0 + c * 16 + l16;
      float bv = bias[col];
#pragma unroll
      for (int i = 0; i < 4; ++i) {
        int row = r0 + s * 16 + qd * 4 + i;
        if (row >= M) continue;
        size_t idx = (size_t)row * NC + col;
        float v = accs[s][c][i] + bv;
        if (mode == GM_F32) outf[idx] = v;
        else if (mode == GM_BF16) outb[idx] = (bf16)v;
        else if (mode == GM_GELU) outb[idx] = (bf16)gelu_f(v);
        else {
          float g = gamma ? gamma[col] : 1.f;
          float r = res[idx] + g * v;
          outf[idx] = r;
          if (mode == GM_RES2) outb[idx] = (bf16)r;
        }
      }
    }
  }
}

// ---------------- batch count: LDS histogram ----------------
__global__ __launch_bounds__(256) void cnt_kernel(const int* __restrict__ batch, float* __restrict__ cntf) {
  __shared__ int hist[BB];
  if (threadIdx.x < BB) hist[threadIdx.x] = 0;
  __syncthreads();
  int n = blockIdx.x * 256 + threadIdx.x;
  if (n < NN) atomicAdd(&hist[batch[n]], 1);
  __syncthreads();
  if (threadIdx.x < BB) {
    int h = hist[threadIdx.x];
    if (h) atomicAdd(&cntf[threadIdx.x], (float)h);
  }
}

// segment-sum x1 rows into per-batch summary; 64 rows per block
__global__ __launch_bounds__(256) void seg_sum(const float* __restrict__ x1,
                                               const int* __restrict__ batch,
                                               float* __restrict__ summary) {
  int r0 = blockIdx.x * 64;
  int t = threadIdx.x;
  float acc = 0.f;
  int curb = batch[r0];
  for (int i = 0; i < 64; ++i) {
    int r = r0 + i;
    int b = batch[r];
    if (b != curb) {
      atomicAdd(&summary[(size_t)curb * DD + t], acc);
      acc = 0.f;
      curb = b;
    }
    acc += x1[(size_t)r * DD + t];
  }
  atomicAdd(&summary[(size_t)curb * DD + t], acc);
}

// ctx = [vn (T rows per b), node_summary/cnt (1 row per b)] as bf16. grid = B*(T+1)
__global__ __launch_bounds__(256) void build_ctx(const float* __restrict__ summary,
                                                 const float* __restrict__ cntf,
                                                 const bf16* __restrict__ vn,
                                                 bf16* __restrict__ ctx) {
  int r = blockIdx.x, t = threadIdx.x;
  int b = r / (TT + 1), k = r % (TT + 1);
  float val;
  if (k < TT) val = (float)vn[((size_t)(b * TT + k)) * DD + t];
  else val = summary[(size_t)b * DD + t] / fmaxf(cntf[b], 1.f);
  ctx[(size_t)r * DD + t] = (bf16)val;
}

// ---------------- small MHA on v (B=8 blocks) ----------------
__global__ __launch_bounds__(256) void mha_small(const float* __restrict__ qh,
                                                 const float* __restrict__ kvh,
                                                 bf16* __restrict__ vatt) {
  int b = blockIdx.x;
  int h = threadIdx.x >> 5, qi = threadIdx.x & 31;
  const float scale = 0.17677669529663687f;
  float sc[TT + 1];
  float mx = -1e30f;
  const float* qp = qh + ((size_t)(b * TT + qi)) * DD + h * HDD;
#pragma unroll
  for (int k = 0; k < TT + 1; ++k) {
    const float* kp = kvh + ((size_t)(b * (TT + 1) + k)) * 512 + h * HDD;
    float s = 0.f;
#pragma unroll
    for (int d = 0; d < HDD; ++d) s += qp[d] * kp[d];
    s *= scale;
    sc[k] = s;
    mx = fmaxf(mx, s);
  }
  float sum = 0.f;
#pragma unroll
  for (int k = 0; k < TT + 1; ++k) {
    sc[k] = __expf(sc[k] - mx);
    sum += sc[k];
  }
  float inv = 1.f / sum;
#pragma unroll
  for (int d = 0; d < HDD; ++d) {
    float o = 0.f;
#pragma unroll
    for (int k = 0; k < TT + 1; ++k)
      o += sc[k] * kvh[((size_t)(b * (TT + 1) + k)) * 512 + 256 + h * HDD + d];
    vatt[((size_t)(b * TT + qi)) * DD + h * HDD + d] = (bf16)(o * inv);
  }
}

// ---------------- per-node cross attention (16 nodes per block) ----------------
__global__ __launch_bounds__(256) void cross_attn(const bf16* __restrict__ qx,
                                                  const float* __restrict__ kvx,
                                                  const int* __restrict__ batch,
                                                  bf16* __restrict__ attnout) {
  __shared__ float v_lds[TT * DD];  // 32 KB
  int tid = threadIdx.x;
  int n0 = blockIdx.x * 16;
  int b0 = batch[n0];
  for (int i = tid; i < TT * DD; i += 256) {
    int t = i >> 8, c = i & 255;
    v_lds[i] = kvx[((size_t)(b0 * TT + t)) * 512 + 256 + c];
  }
  int h = tid >> 5, lt = tid & 31;
  float kreg[HDD];
  {
    const float* kp = kvx + ((size_t)(b0 * TT + lt)) * 512 + h * HDD;
#pragma unroll
    for (int d = 0; d < HDD; ++d) kreg[d] = kp[d];
  }
  __syncthreads();
  const float scale = 0.17677669529663687f;
  for (int ni = 0; ni < 16; ++ni) {
    int n = n0 + ni;
    int b = batch[n];
    const bf16* qp = qx + (size_t)n * DD + h * HDD;
    float s = 0.f;
    if (b == b0) {
#pragma unroll
      for (int d = 0; d < HDD; ++d) s += (float)qp[d] * kreg[d];
    } else {
      const float* kp = kvx + ((size_t)(b * TT + lt)) * 512 + h * HDD;
#pragma unroll
      for (int d = 0; d < HDD; ++d) s += (float)qp[d] * kp[d];
    }
    s *= scale;
    float mx = s;
#pragma unroll
    for (int o = 16; o > 0; o >>= 1) mx = fmaxf(mx, __shfl_xor(mx, o, 32));
    float e = __expf(s - mx);
    float sum = e;
#pragma unroll
    for (int o = 16; o > 0; o >>= 1) sum += __shfl_xor(sum, o, 32);
    float a = e / sum;
    float o_acc = 0.f;
    int base_lane = (h & 1) << 5;
    if (b == b0) {
#pragma unroll
      for (int t = 0; t < TT; ++t) {
        float at = __shfl(a, base_lane + t, 64);
        o_acc += at * v_lds[t * DD + h * HDD + lt];
      }
    } else {
#pragma unroll
      for (int t = 0; t < TT; ++t) {
        float at = __shfl(a, base_lane + t, 64);
        o_acc += at * kvx[((size_t)(b * TT + t)) * 512 + 256 + h * HDD + lt];
      }
    }
    attnout[(size_t)n * DD + h * HDD + lt] = (bf16)o_acc;
  }
}

// ---------------- host launch ----------------
extern "C" void kernel_launch(void* const* d_in, const int* in_sizes, int n_in,
                              void* d_out, int out_size, void* d_ws, size_t ws_size,
                              hipStream_t stream) {
  const float* x = (const float*)d_in[0];
  const int* ei = (const int*)d_in[1];
  const float* eattr = (const float*)d_in[2];
  const float* v = (const float*)d_in[3];
  const int* batch = (const int*)d_in[4];
  const float* n1_g = (const float*)d_in[5];
  const float* n1_b = (const float*)d_in[6];
  const float* vn_g = (const float*)d_in[7];
  const float* vn_b = (const float*)d_in[8];
  const float* n3_g = (const float*)d_in[9];
  const float* n3_b = (const float*)d_in[10];
  const float* n4_g = (const float*)d_in[11];
  const float* n4_b = (const float*)d_in[12];
  const float* gine_eps = (const float*)d_in[13];
  const float* g_w1 = (const float*)d_in[14];
  const float* g_b1 = (const float*)d_in[15];
  const float* g_lng = (const float*)d_in[16];
  const float* g_lnb = (const float*)d_in[17];
  const float* g_w2 = (const float*)d_in[18];
  const float* g_b2 = (const float*)d_in[19];
  const float* gamma1 = (const float*)d_in[20];
  const float* gamma2 = (const float*)d_in[21];
  const float* gamma3 = (const float*)d_in[22];
  const float* mha_in_w = (const float*)d_in[23];
  const float* mha_in_b = (const float*)d_in[24];
  const float* mha_out_w = (const float*)d_in[25];
  const float* mha_out_b = (const float*)d_in[26];
  const float* q_w = (const float*)d_in[27];
  const float* q_b = (const float*)d_in[28];
  const float* kv_w = (const float*)d_in[29];
  const float* kv_b = (const float*)d_in[30];
  const float* o_w = (const float*)d_in[31];
  const float* o_b = (const float*)d_in[32];
  const float* f_w1 = (const float*)d_in[33];
  const float* f_b1 = (const float*)d_in[34];
  const float* f_w2 = (const float*)d_in[35];
  const float* f_b2 = (const float*)d_in[36];

  float* out_x = (float*)d_out;
  float* out_v = (float*)d_out + (size_t)NN * DD;

  char* wsp = (char*)d_ws;
  size_t off = 0;
  auto alloc = [&](size_t bytes) -> void* {
    void* p = wsp + off;
    off += (bytes + 255) & ~(size_t)255;
    return p;
  };
  // aliased arenas (lifetimes disjoint)
  float* t1f = (float*)alloc(33554432);  // S1: t1 f32 (N x 512) -> later u bf16 (N x 1024)
  bf16* u_bf = (bf16*)t1f;
  bf16* xn_bf = (bf16*)alloc(8388608);   // S2: xn -> later qx
  bf16* qx_bf = xn_bf;
  bf16* t1g_bf = (bf16*)alloc(16777216); // S3: t1g bf16 -> later x2 f32
  float* x2f = (float*)t1g_bf;
  float* x1f = (float*)alloc(16777216);  // S4
  bf16* hin_bf = (bf16*)alloc(8388608);  // S5: hin -> later xn3
  bf16* xn3_bf = hin_bf;
  bf16* att_bf = (bf16*)alloc(8388608);  // S6: attnout -> later xn4
  bf16* xn4_bf = att_bf;
  int* deg = (int*)alloc(NN * 4);
  int* offs = (int*)alloc((NN + 1) * 4);
  int* woff = (int*)alloc(NN * 4);
  int2* csr2 = (int2*)alloc((size_t)EE * 8);
  float* summary = (float*)alloc(BB * DD * 4);
  float* cntf = (float*)alloc(BB * 4);
  bf16* vn_bf = (bf16*)alloc(BB * TT * DD * 2);
  bf16* ctx_bf = (bf16*)alloc(BB * (TT + 1) * DD * 2);
  float* qhf = (float*)alloc(BB * TT * DD * 4);
  float* kvhf = (float*)alloc(BB * (TT + 1) * 512 * 4);
  bf16* vatt_bf = (bf16*)alloc(BB * TT * DD * 2);
  bf16* vout_bf = (bf16*)alloc(BB * TT * DD * 2);
  float* kvxf = (float*)alloc(BB * TT * 512 * 4);
  bf16* wbuf = (bf16*)alloc((size_t)1310720 * 2);

  bf16* g_w1b = wbuf;
  bf16* g_w2b = g_w1b + 131072;
  bf16* mha_in_wb = g_w2b + 131072;
  bf16* mha_out_wb = mha_in_wb + 196608;
  bf16* q_wb = mha_out_wb + 65536;
  bf16* kv_wb = q_wb + 65536;
  bf16* o_wb = kv_wb + 131072;
  bf16* f_w1b = o_wb + 65536;
  bf16* f_w2b = f_w1b + 262144;

  // 0. weight casts + scratch zeroing
  Cast9 cj;
  cj.src[0] = g_w1; cj.dst[0] = g_w1b;
  cj.src[1] = g_w2; cj.dst[1] = g_w2b;
  cj.src[2] = mha_in_w; cj.dst[2] = mha_in_wb;
  cj.src[3] = mha_out_w; cj.dst[3] = mha_out_wb;
  cj.src[4] = q_w; cj.dst[4] = q_wb;
  cj.src[5] = kv_w; cj.dst[5] = kv_wb;
  cj.src[6] = o_w; cj.dst[6] = o_wb;
  cj.src[7] = f_w1; cj.dst[7] = f_w1b;
  cj.src[8] = f_w2; cj.dst[8] = f_w2b;
  int bs[10] = {0, 128, 256, 448, 512, 576, 704, 768, 1024, 1280};
  for (int i = 0; i < 10; ++i) cj.blk_start[i] = bs[i];
  cast9<<<1280, 256, 0, stream>>>(cj);
  zero_bufs<<<73, 256, 0, stream>>>(deg, summary, cntf);

  // 1. xn = LN(x)
  ln_rows<<<NN, 256, 0, stream>>>(x, n1_g, n1_b, xn_bf, DD, 0);

  // 2. CSR by destination
  deg_count<<<EE / 256, 256, 0, stream>>>(ei, deg);
  scan16k<<<1, 1024, 0, stream>>>(deg, offs, woff);
  csr_fill<<<EE / 256, 256, 0, stream>>>(ei, woff, csr2);

  // 3. GINE aggregation -> hin (bf16)
  gine_agg<<<NN, 256, 0, stream>>>(eattr, xn_bf, offs, csr2, gine_eps, hin_bf);

  // 4. GINE MLP
  gemm_bt<<<dim3(8, 128), 256, 0, stream>>>(hin_bf, g_w1b, g_b1, NN, 256, 512, GM_F32,
                                            nullptr, nullptr, t1f, nullptr);
  ln_rows<<<NN, 256, 0, stream>>>(t1f, g_lng, g_lnb, t1g_bf, 512, 1);
  gemm_bt<<<dim3(4, 128), 256, 0, stream>>>(t1g_bf, g_w2b, g_b2, NN, 512, 256, GM_RES,
                                            x, gamma1, x1f, nullptr);

  // 5. node summary over batch
  cnt_kernel<<<NN / 256, 256, 0, stream>>>(batch, cntf);
  seg_sum<<<NN / 64, 256, 0, stream>>>(x1f, batch, summary);

  // 6. small MHA over v
  ln_rows<<<BB * TT, 256, 0, stream>>>(v, vn_g, vn_b, vn_bf, DD, 0);
  build_ctx<<<BB * (TT + 1), 256, 0, stream>>>(summary, cntf, vn_bf, ctx_bf);
  gemm_bt<<<dim3(4, 2), 256, 0, stream>>>(vn_bf, mha_in_wb, mha_in_b, BB * TT, 256, 256,
                                          GM_F32, nullptr, nullptr, qhf, nullptr);
  gemm_bt<<<dim3(8, 3), 256, 0, stream>>>(ctx_bf, mha_in_wb + (size_t)256 * 256,
                                          mha_in_b + 256, BB * (TT + 1), 256, 512,
                                          GM_F32, nullptr, nullptr, kvhf, nullptr);
  mha_small<<<BB, 256, 0, stream>>>(qhf, kvhf, vatt_bf);
  gemm_bt<<<dim3(4, 2), 256, 0, stream>>>(vatt_bf, mha_out_wb, mha_out_b, BB * TT, 256, 256,
                                          GM_RES2, v, gamma2, out_v, vout_bf);

  // 7. cross attention x <- v
  gemm_bt<<<dim3(8, 2), 256, 0, stream>>>(vout_bf, kv_wb, kv_b, BB * TT, 256, 512,
                                          GM_F32, nullptr, nullptr, kvxf, nullptr);
  ln_rows<<<NN, 256, 0, stream>>>(x1f, n3_g, n3_b, xn3_bf, DD, 0);
  gemm_bt<<<dim3(4, 128), 256, 0, stream>>>(xn3_bf, q_wb, q_b, NN, 256, 256, GM_BF16,
                                            nullptr, nullptr, nullptr, qx_bf);
  cross_attn<<<NN / 16, 256, 0, stream>>>(qx_bf, kvxf, batch, att_bf);
  gemm_bt<<<dim3(4, 128), 256, 0, stream>>>(att_bf, o_wb, o_b, NN, 256, 256, GM_RES,
                                            x1f, gamma3, x2f, nullptr);

  // 8. FFN
  ln_rows<<<NN, 256, 0, stream>>>(x2f, n4_g, n4_b, xn4_bf, DD, 0);
  gemm_bt<<<dim3(16, 128), 256, 0, stream>>>(xn4_bf, f_w1b, f_b1, NN, 256, 1024, GM_GELU,
                                             nullptr, nullptr, nullptr, u_bf);
  gemm_bt<<<dim3(4, 128), 256, 0, stream>>>(u_bf, f_w2b, f_b2, NN, 1024, 256, GM_RES,
                                            x2f, nullptr, out_x, nullptr);
}

// Round 4
// 944.047 us; speedup vs baseline: 1.3687x; 1.0166x over previous
//
#include <hip/hip_runtime.h>
#include <math.h>

#define NN 16384
#define EE 262144
#define BB 8
#define TT 32
#define DD 256
#define HH 8
#define HDD 32

typedef __bf16 bf16;
typedef __bf16 bf16x8 __attribute__((ext_vector_type(8)));
typedef __bf16 bf16x4 __attribute__((ext_vector_type(4)));
typedef float f32x4 __attribute__((ext_vector_type(4)));

#define GM_F32 0
#define GM_BF16 1
#define GM_GELU 2
#define GM_RES 3
#define GM_RES2 4

__device__ __forceinline__ float gelu_f(float v) {
  return 0.5f * v * (1.f + erff(v * 0.70710678118654752440f));
}

// ---------------- LN for one 256-wide row (256 threads) ----------------
__device__ __forceinline__ void ln256(const float* __restrict__ xr,
                                      const float* __restrict__ g,
                                      const float* __restrict__ bb,
                                      bf16* __restrict__ o, float* red) {
  int t = threadIdx.x;
  float v = xr[t];
  float s = v, s2 = v * v;
#pragma unroll
  for (int off = 32; off > 0; off >>= 1) {
    s += __shfl_down(s, off, 64);
    s2 += __shfl_down(s2, off, 64);
  }
  int wv = t >> 6;
  if ((t & 63) == 0) { red[wv] = s; red[4 + wv] = s2; }
  __syncthreads();
  s = red[0] + red[1] + red[2] + red[3];
  s2 = red[4] + red[5] + red[6] + red[7];
  float m = s * (1.f / 256.f);
  float rs = rsqrtf(s2 * (1.f / 256.f) - m * m + 1e-5f);
  o[t] = (bf16)((v - m) * rs * g[t] + bb[t]);
}

// ---------------- fused prologue: cast9 | LN(x) | LN(v) | cnt | deg ----------------
// block ranges: [0,1280) cast, [1280,17664) LN x, [17664,17920) LN v,
//               [17920,17984) cnt, [17984,19008) deg_count
struct Pro {
  const float* wsrc[9];
  bf16* wdst[9];
  int wblk[10];
  const float* x; const float* n1_g; const float* n1_b; bf16* xn;
  const float* v; const float* vn_g; const float* vn_b; bf16* vn;
  const int* batch; float* cntf;
  const int* ei; int* deg;
};

__global__ __launch_bounds__(256) void prologue(Pro p) {
  __shared__ float red[8];
  __shared__ int hist[BB];
  int b = blockIdx.x, t = threadIdx.x;
  if (b < 1280) {
    int s = 0;
    while (b >= p.wblk[s + 1]) ++s;
    int i = (b - p.wblk[s]) * 1024 + t * 4;
    const float4 f = *(const float4*)(p.wsrc[s] + i);
    bf16x4 o;
    o[0] = (bf16)f.x; o[1] = (bf16)f.y; o[2] = (bf16)f.z; o[3] = (bf16)f.w;
    *(bf16x4*)(p.wdst[s] + i) = o;
  } else if (b < 17664) {
    size_t r = b - 1280;
    ln256(p.x + r * 256, p.n1_g, p.n1_b, p.xn + r * 256, red);
  } else if (b < 17920) {
    size_t r = b - 17664;
    ln256(p.v + r * 256, p.vn_g, p.vn_b, p.vn + r * 256, red);
  } else if (b < 17984) {
    if (t < BB) hist[t] = 0;
    __syncthreads();
    int n = (b - 17920) * 256 + t;
    atomicAdd(&hist[p.batch[n]], 1);
    __syncthreads();
    if (t < BB) {
      int h = hist[t];
      if (h) atomicAdd(&p.cntf[t], (float)h);
    }
  } else {
    int e = (b - 17984) * 256 + t;
    atomicAdd(&p.deg[p.ei[EE + e]], 1);
  }
}

// ---------------- CSR build ----------------
__global__ __launch_bounds__(1024) void scan16k(const int* __restrict__ deg,
                                                int* __restrict__ offs, int* __restrict__ woff) {
  __shared__ int part[1024];
  int t = threadIdx.x;
  int base = t * 16;
  int v[16];
  int s = 0;
#pragma unroll
  for (int j = 0; j < 16; ++j) { v[j] = deg[base + j]; s += v[j]; }
  part[t] = s;
  __syncthreads();
  for (int o = 1; o < 1024; o <<= 1) {
    int x = (t >= o) ? part[t - o] : 0;
    __syncthreads();
    part[t] += x;
    __syncthreads();
  }
  int excl = part[t] - s;
#pragma unroll
  for (int j = 0; j < 16; ++j) {
    offs[base + j] = excl;
    woff[base + j] = excl;
    excl += v[j];
  }
  if (t == 1023) offs[NN] = part[1023];
}

__global__ __launch_bounds__(256) void csr_fill(const int* __restrict__ ei, int* __restrict__ woff,
                                                int2* __restrict__ csr2) {
  int e = blockIdx.x * 256 + threadIdx.x;
  if (e < EE) {
    int d = ei[EE + e];
    int s = ei[e];
    int p = atomicAdd(&woff[d], 1);
    csr2[p] = make_int2(e, s);
  }
}

// GINE aggregation: block per node, wave per edge (4 in flight), lane covers 4 channels.
__global__ __launch_bounds__(256) void gine_agg(const float* __restrict__ eattr,
                                                const bf16* __restrict__ xn,
                                                const int* __restrict__ offs,
                                                const int2* __restrict__ csr2,
                                                const float* __restrict__ epsp,
                                                bf16* __restrict__ hin) {
  __shared__ f32x4 red[4][64];
  int n = blockIdx.x;
  int wave = threadIdx.x >> 6, lane = threadIdx.x & 63;
  int s0 = offs[n], s1 = offs[n + 1];
  f32x4 acc = {0.f, 0.f, 0.f, 0.f};
  int i = s0 + wave;
  int2 es = (i < s1) ? csr2[i] : make_int2(0, 0);
  for (; i < s1; i += 4) {
    int2 cur = es;
    int inext = i + 4;
    if (inext < s1) es = csr2[inext];
    float4 ea = *(const float4*)(eattr + (size_t)cur.x * DD + lane * 4);
    bf16x4 xv = *(const bf16x4*)(xn + (size_t)cur.y * DD + lane * 4);
    acc[0] += fmaxf((float)xv[0] + ea.x, 0.f);
    acc[1] += fmaxf((float)xv[1] + ea.y, 0.f);
    acc[2] += fmaxf((float)xv[2] + ea.z, 0.f);
    acc[3] += fmaxf((float)xv[3] + ea.w, 0.f);
  }
  red[wave][lane] = acc;
  __syncthreads();
  if (wave == 0) {
    f32x4 a = red[0][lane];
    f32x4 a1 = red[1][lane], a2 = red[2][lane], a3 = red[3][lane];
    bf16x4 xs = *(const bf16x4*)(xn + (size_t)n * DD + lane * 4);
    float e1 = 1.f + epsp[0];
    bf16x4 o;
#pragma unroll
    for (int j = 0; j < 4; ++j)
      o[j] = (bf16)(e1 * (float)xs[j] + a[j] + a1[j] + a2[j] + a3[j]);
    *(bf16x4*)(hin + (size_t)n * DD + lane * 4) = o;
  }
}

// ---------------- MFMA GEMM core with register double-buffer prefetch ----------------
// wave computes 32 rows x 64 cols; block = 4 waves = 128 rows x 64 cols.
struct GemmP {
  const bf16* A; const bf16* W; const float* bias;
  int M, K, NC, mode;
  const float* res; const float* gamma;
  float* outf; bf16* outb;
};

__device__ __forceinline__ void gemm_core(const GemmP p, int bx, int by) {
  int wave = threadIdx.x >> 6;
  int lane = threadIdx.x & 63;
  int qd = lane >> 4;
  int l16 = lane & 15;
  int r0 = by * 128 + wave * 32;
  int c0 = bx * 64;
  int ar0 = r0 + l16;       if (ar0 >= p.M) ar0 = p.M - 1;
  int ar1 = r0 + 16 + l16;  if (ar1 >= p.M) ar1 = p.M - 1;
  const bf16* Ap0 = p.A + (size_t)ar0 * p.K + qd * 8;
  const bf16* Ap1 = p.A + (size_t)ar1 * p.K + qd * 8;
  const bf16* Wp = p.W + (size_t)(c0 + l16) * p.K + qd * 8;
  size_t K16 = (size_t)16 * p.K;
  f32x4 acc00 = {0.f, 0.f, 0.f, 0.f};
  f32x4 acc01 = acc00, acc02 = acc00, acc03 = acc00;
  f32x4 acc10 = acc00, acc11 = acc00, acc12 = acc00, acc13 = acc00;
  bf16x8 a0, a1, b0, b1, b2, b3, na0, na1, nb0, nb1, nb2, nb3;

#define GLOADS(A0, A1, B0, B1, B2, B3, kk)                \
  A0 = *(const bf16x8*)(Ap0 + (kk));                      \
  A1 = *(const bf16x8*)(Ap1 + (kk));                      \
  B0 = *(const bf16x8*)(Wp + (kk));                       \
  B1 = *(const bf16x8*)(Wp + K16 + (kk));                 \
  B2 = *(const bf16x8*)(Wp + 2 * K16 + (kk));             \
  B3 = *(const bf16x8*)(Wp + 3 * K16 + (kk));
#define GMFMAS(A0, A1, B0, B1, B2, B3)                                  \
  acc00 = __builtin_amdgcn_mfma_f32_16x16x32_bf16(A0, B0, acc00, 0, 0, 0); \
  acc01 = __builtin_amdgcn_mfma_f32_16x16x32_bf16(A0, B1, acc01, 0, 0, 0); \
  acc02 = __builtin_amdgcn_mfma_f32_16x16x32_bf16(A0, B2, acc02, 0, 0, 0); \
  acc03 = __builtin_amdgcn_mfma_f32_16x16x32_bf16(A0, B3, acc03, 0, 0, 0); \
  acc10 = __builtin_amdgcn_mfma_f32_16x16x32_bf16(A1, B0, acc10, 0, 0, 0); \
  acc11 = __builtin_amdgcn_mfma_f32_16x16x32_bf16(A1, B1, acc11, 0, 0, 0); \
  acc12 = __builtin_amdgcn_mfma_f32_16x16x32_bf16(A1, B2, acc12, 0, 0, 0); \
  acc13 = __builtin_amdgcn_mfma_f32_16x16x32_bf16(A1, B3, acc13, 0, 0, 0);

  GLOADS(a0, a1, b0, b1, b2, b3, 0)
  int k = 32;
  // K/32 is even for all shapes here (K in {256,512,1024})
  for (; k + 32 < p.K; k += 64) {
    GLOADS(na0, na1, nb0, nb1, nb2, nb3, k)
    GMFMAS(a0, a1, b0, b1, b2, b3)
    GLOADS(a0, a1, b0, b1, b2, b3, k + 32)
    GMFMAS(na0, na1, nb0, nb1, nb2, nb3)
  }
  GLOADS(na0, na1, nb0, nb1, nb2, nb3, k)
  GMFMAS(a0, a1, b0, b1, b2, b3)
  GMFMAS(na0, na1, nb0, nb1, nb2, nb3)
#undef GLOADS
#undef GMFMAS

  f32x4 accs[2][4] = {{acc00, acc01, acc02, acc03}, {acc10, acc11, acc12, acc13}};
#pragma unroll
  for (int s = 0; s < 2; ++s) {
#pragma unroll
    for (int c = 0; c < 4; ++c) {
      int col = c0 + c * 16 + l16;
      float bv = p.bias[col];
#pragma unroll
      for (int i = 0; i < 4; ++i) {
        int row = r0 + s * 16 + qd * 4 + i;
        if (row >= p.M) continue;
        size_t idx = (size_t)row * p.NC + col;
        float v = accs[s][c][i] + bv;
        if (p.mode == GM_F32) p.outf[idx] = v;
        else if (p.mode == GM_BF16) p.outb[idx] = (bf16)v;
        else if (p.mode == GM_GELU) p.outb[idx] = (bf16)gelu_f(v);
        else {
          float g = p.gamma ? p.gamma[col] : 1.f;
          float r = p.res[idx] + g * v;
          p.outf[idx] = r;
          if (p.mode == GM_RES2) p.outb[idx] = (bf16)r;
        }
      }
    }
  }
}

__global__ __launch_bounds__(256) void gemm_one(GemmP p, int nbx) {
  gemm_core(p, blockIdx.x % nbx, blockIdx.x / nbx);
}

__global__ __launch_bounds__(256) void gemm_dual(GemmP p0, int nblk0, int nbx0,
                                                 GemmP p1, int nbx1) {
  int b = blockIdx.x;
  if (b < nblk0) gemm_core(p0, b % nbx0, b / nbx0);
  else {
    b -= nblk0;
    gemm_core(p1, b % nbx1, b / nbx1);
  }
}

// ---------------- LN for 512-wide rows with gelu (t1 -> t1g) ----------------
__global__ __launch_bounds__(256) void ln512_gelu(const float* __restrict__ in,
                                                  const float* __restrict__ g,
                                                  const float* __restrict__ b,
                                                  bf16* __restrict__ out) {
  int row = blockIdx.x;
  int t = threadIdx.x;
  const float* x = in + (size_t)row * 512;
  float v0 = x[t], v1 = x[256 + t];
  float s = v0 + v1, s2 = v0 * v0 + v1 * v1;
#pragma unroll
  for (int o = 32; o > 0; o >>= 1) {
    s += __shfl_down(s, o, 64);
    s2 += __shfl_down(s2, o, 64);
  }
  __shared__ float red[8];
  int wv = t >> 6;
  if ((t & 63) == 0) { red[wv] = s; red[4 + wv] = s2; }
  __syncthreads();
  s = red[0] + red[1] + red[2] + red[3];
  s2 = red[4] + red[5] + red[6] + red[7];
  float m = s * (1.f / 512.f);
  float rs = rsqrtf(s2 * (1.f / 512.f) - m * m + 1e-5f);
  out[(size_t)row * 512 + t] = (bf16)gelu_f((v0 - m) * rs * g[t] + b[t]);
  out[(size_t)row * 512 + 256 + t] = (bf16)gelu_f((v1 - m) * rs * g[256 + t] + b[256 + t]);
}

// ---------------- mid1: seg_sum [0,256) + LN3 [256,16640) ----------------
__global__ __launch_bounds__(256) void mid1(const float* __restrict__ x1,
                                            const int* __restrict__ batch,
                                            float* __restrict__ summary,
                                            const float* __restrict__ n3_g,
                                            const float* __restrict__ n3_b,
                                            bf16* __restrict__ xn3) {
  __shared__ float red[8];
  int b = blockIdx.x, t = threadIdx.x;
  if (b < 256) {
    int r0 = b * 64;
    float acc = 0.f;
    int curb = batch[r0];
    for (int i = 0; i < 64; ++i) {
      int r = r0 + i;
      int bb = batch[r];
      if (bb != curb) {
        atomicAdd(&summary[(size_t)curb * DD + t], acc);
        acc = 0.f;
        curb = bb;
      }
      acc += x1[(size_t)r * DD + t];
    }
    atomicAdd(&summary[(size_t)curb * DD + t], acc);
  } else {
    size_t r = b - 256;
    ln256(x1 + r * 256, n3_g, n3_b, xn3 + r * 256, red);
  }
}

// ---------------- mid2: build_ctx [0,264) + q-gemm [264,776) ----------------
__global__ __launch_bounds__(256) void mid2(const float* __restrict__ summary,
                                            const float* __restrict__ cntf,
                                            const bf16* __restrict__ vn,
                                            bf16* __restrict__ ctx,
                                            GemmP qp) {
  int b = blockIdx.x, t = threadIdx.x;
  if (b < BB * (TT + 1)) {
    int bb = b / (TT + 1), k = b % (TT + 1);
    float val;
    if (k < TT) val = (float)vn[((size_t)(bb * TT + k)) * DD + t];
    else val = summary[(size_t)bb * DD + t] / fmaxf(cntf[bb], 1.f);
    ctx[(size_t)b * DD + t] = (bf16)val;
  } else {
    int l = b - BB * (TT + 1);
    gemm_core(qp, l % 4, l / 4);
  }
}

// ---------------- small MHA on v (B=8 blocks) ----------------
__global__ __launch_bounds__(256) void mha_small(const float* __restrict__ qh,
                                                 const float* __restrict__ kvh,
                                                 bf16* __restrict__ vatt) {
  int b = blockIdx.x;
  int h = threadIdx.x >> 5, qi = threadIdx.x & 31;
  const float scale = 0.17677669529663687f;
  float sc[TT + 1];
  float mx = -1e30f;
  const float* qp = qh + ((size_t)(b * TT + qi)) * DD + h * HDD;
#pragma unroll
  for (int k = 0; k < TT + 1; ++k) {
    const float* kp = kvh + ((size_t)(b * (TT + 1) + k)) * 512 + h * HDD;
    float s = 0.f;
#pragma unroll
    for (int d = 0; d < HDD; ++d) s += qp[d] * kp[d];
    s *= scale;
    sc[k] = s;
    mx = fmaxf(mx, s);
  }
  float sum = 0.f;
#pragma unroll
  for (int k = 0; k < TT + 1; ++k) {
    sc[k] = __expf(sc[k] - mx);
    sum += sc[k];
  }
  float inv = 1.f / sum;
#pragma unroll
  for (int d = 0; d < HDD; ++d) {
    float o = 0.f;
#pragma unroll
    for (int k = 0; k < TT + 1; ++k)
      o += sc[k] * kvh[((size_t)(b * (TT + 1) + k)) * 512 + 256 + h * HDD + d];
    vatt[((size_t)(b * TT + qi)) * DD + h * HDD + d] = (bf16)(o * inv);
  }
}

// ---------------- per-node cross attention (16 nodes per block) ----------------
__global__ __launch_bounds__(256) void cross_attn(const bf16* __restrict__ qx,
                                                  const float* __restrict__ kvx,
                                                  const int* __restrict__ batch,
                                                  bf16* __restrict__ attnout) {
  __shared__ float v_lds[TT * DD];  // 32 KB
  int tid = threadIdx.x;
  int n0 = blockIdx.x * 16;
  int b0 = batch[n0];
  for (int i = tid; i < TT * DD; i += 256) {
    int t = i >> 8, c = i & 255;
    v_lds[i] = kvx[((size_t)(b0 * TT + t)) * 512 + 256 + c];
  }
  int h = tid >> 5, lt = tid & 31;
  float kreg[HDD];
  {
    const float* kp = kvx + ((size_t)(b0 * TT + lt)) * 512 + h * HDD;
#pragma unroll
    for (int d = 0; d < HDD; ++d) kreg[d] = kp[d];
  }
  __syncthreads();
  const float scale = 0.17677669529663687f;
  for (int ni = 0; ni < 16; ++ni) {
    int n = n0 + ni;
    int b = batch[n];
    const bf16* qp = qx + (size_t)n * DD + h * HDD;
    float s = 0.f;
    if (b == b0) {
#pragma unroll
      for (int d = 0; d < HDD; ++d) s += (float)qp[d] * kreg[d];
    } else {
      const float* kp = kvx + ((size_t)(b * TT + lt)) * 512 + h * HDD;
#pragma unroll
      for (int d = 0; d < HDD; ++d) s += (float)qp[d] * kp[d];
    }
    s *= scale;
    float mx = s;
#pragma unroll
    for (int o = 16; o > 0; o >>= 1) mx = fmaxf(mx, __shfl_xor(mx, o, 32));
    float e = __expf(s - mx);
    float sum = e;
#pragma unroll
    for (int o = 16; o > 0; o >>= 1) sum += __shfl_xor(sum, o, 32);
    float a = e / sum;
    float o_acc = 0.f;
    int base_lane = (h & 1) << 5;
    if (b == b0) {
#pragma unroll
      for (int t = 0; t < TT; ++t) {
        float at = __shfl(a, base_lane + t, 64);
        o_acc += at * v_lds[t * DD + h * HDD + lt];
      }
    } else {
#pragma unroll
      for (int t = 0; t < TT; ++t) {
        float at = __shfl(a, base_lane + t, 64);
        o_acc += at * kvx[((size_t)(b * TT + t)) * 512 + 256 + h * HDD + lt];
      }
    }
    attnout[(size_t)n * DD + h * HDD + lt] = (bf16)o_acc;
  }
}

// ---------------- LN4 standalone (x2 -> xn4) ----------------
__global__ __launch_bounds__(256) void ln4_k(const float* __restrict__ in,
                                             const float* __restrict__ g,
                                             const float* __restrict__ b,
                                             bf16* __restrict__ out) {
  __shared__ float red[8];
  size_t r = blockIdx.x;
  ln256(in + r * 256, g, b, out + r * 256, red);
}

// ---------------- host launch ----------------
extern "C" void kernel_launch(void* const* d_in, const int* in_sizes, int n_in,
                              void* d_out, int out_size, void* d_ws, size_t ws_size,
                              hipStream_t stream) {
  const float* x = (const float*)d_in[0];
  const int* ei = (const int*)d_in[1];
  const float* eattr = (const float*)d_in[2];
  const float* v = (const float*)d_in[3];
  const int* batch = (const int*)d_in[4];
  const float* n1_g = (const float*)d_in[5];
  const float* n1_b = (const float*)d_in[6];
  const float* vn_g = (const float*)d_in[7];
  const float* vn_b = (const float*)d_in[8];
  const float* n3_g = (const float*)d_in[9];
  const float* n3_b = (const float*)d_in[10];
  const float* n4_g = (const float*)d_in[11];
  const float* n4_b = (const float*)d_in[12];
  const float* gine_eps = (const float*)d_in[13];
  const float* g_w1 = (const float*)d_in[14];
  const float* g_b1 = (const float*)d_in[15];
  const float* g_lng = (const float*)d_in[16];
  const float* g_lnb = (const float*)d_in[17];
  const float* g_w2 = (const float*)d_in[18];
  const float* g_b2 = (const float*)d_in[19];
  const float* gamma1 = (const float*)d_in[20];
  const float* gamma2 = (const float*)d_in[21];
  const float* gamma3 = (const float*)d_in[22];
  const float* mha_in_w = (const float*)d_in[23];
  const float* mha_in_b = (const float*)d_in[24];
  const float* mha_out_w = (const float*)d_in[25];
  const float* mha_out_b = (const float*)d_in[26];
  const float* q_w = (const float*)d_in[27];
  const float* q_b = (const float*)d_in[28];
  const float* kv_w = (const float*)d_in[29];
  const float* kv_b = (const float*)d_in[30];
  const float* o_w = (const float*)d_in[31];
  const float* o_b = (const float*)d_in[32];
  const float* f_w1 = (const float*)d_in[33];
  const float* f_b1 = (const float*)d_in[34];
  const float* f_w2 = (const float*)d_in[35];
  const float* f_b2 = (const float*)d_in[36];

  float* out_x = (float*)d_out;
  float* out_v = (float*)d_out + (size_t)NN * DD;

  char* wsp = (char*)d_ws;
  size_t off = 0;
  auto alloc = [&](size_t bytes) -> void* {
    void* p = wsp + off;
    off += (bytes + 255) & ~(size_t)255;
    return p;
  };
  // aliased arenas (lifetimes disjoint)
  float* t1f = (float*)alloc(33554432);  // S1: t1 f32 (N x 512) -> later u bf16 (N x 1024)
  bf16* u_bf = (bf16*)t1f;
  bf16* xn_bf = (bf16*)alloc(8388608);   // S2: xn -> later qx
  bf16* qx_bf = xn_bf;
  bf16* t1g_bf = (bf16*)alloc(16777216); // S3: t1g bf16 -> later x2 f32
  float* x2f = (float*)t1g_bf;
  float* x1f = (float*)alloc(16777216);  // S4
  bf16* hin_bf = (bf16*)alloc(8388608);  // S5: hin -> later xn3
  bf16* xn3_bf = hin_bf;
  bf16* att_bf = (bf16*)alloc(8388608);  // S6: attnout -> later xn4
  bf16* xn4_bf = att_bf;
  // contiguous zero region: deg | summary | cntf
  int* deg = (int*)alloc(NN * 4);
  float* summary = (float*)alloc(BB * DD * 4);
  float* cntf = (float*)alloc(BB * 4);
  int* offs = (int*)alloc((NN + 1) * 4);
  int* woff = (int*)alloc(NN * 4);
  int2* csr2 = (int2*)alloc((size_t)EE * 8);
  bf16* vn_bf = (bf16*)alloc(BB * TT * DD * 2);
  bf16* ctx_bf = (bf16*)alloc(BB * (TT + 1) * DD * 2);
  float* qhf = (float*)alloc(BB * TT * DD * 4);
  float* kvhf = (float*)alloc(BB * (TT + 1) * 512 * 4);
  bf16* vatt_bf = (bf16*)alloc(BB * TT * DD * 2);
  bf16* vout_bf = (bf16*)alloc(BB * TT * DD * 2);
  float* kvxf = (float*)alloc(BB * TT * 512 * 4);
  bf16* wbuf = (bf16*)alloc((size_t)1310720 * 2);

  bf16* g_w1b = wbuf;
  bf16* g_w2b = g_w1b + 131072;
  bf16* mha_in_wb = g_w2b + 131072;
  bf16* mha_out_wb = mha_in_wb + 196608;
  bf16* q_wb = mha_out_wb + 65536;
  bf16* kv_wb = q_wb + 65536;
  bf16* o_wb = kv_wb + 131072;
  bf16* f_w1b = o_wb + 65536;
  bf16* f_w2b = f_w1b + 262144;

  // 0. zero deg+summary+cntf (contiguous; alloc pads each to 256B)
  hipMemsetAsync(deg, 0, NN * 4 + BB * DD * 4 + 256, stream);

  // 1. fused prologue
  Pro pr;
  pr.wsrc[0] = g_w1; pr.wdst[0] = g_w1b;
  pr.wsrc[1] = g_w2; pr.wdst[1] = g_w2b;
  pr.wsrc[2] = mha_in_w; pr.wdst[2] = mha_in_wb;
  pr.wsrc[3] = mha_out_w; pr.wdst[3] = mha_out_wb;
  pr.wsrc[4] = q_w; pr.wdst[4] = q_wb;
  pr.wsrc[5] = kv_w; pr.wdst[5] = kv_wb;
  pr.wsrc[6] = o_w; pr.wdst[6] = o_wb;
  pr.wsrc[7] = f_w1; pr.wdst[7] = f_w1b;
  pr.wsrc[8] = f_w2; pr.wdst[8] = f_w2b;
  int bs[10] = {0, 128, 256, 448, 512, 576, 704, 768, 1024, 1280};
  for (int i = 0; i < 10; ++i) pr.wblk[i] = bs[i];
  pr.x = x; pr.n1_g = n1_g; pr.n1_b = n1_b; pr.xn = xn_bf;
  pr.v = v; pr.vn_g = vn_g; pr.vn_b = vn_b; pr.vn = vn_bf;
  pr.batch = batch; pr.cntf = cntf;
  pr.ei = ei; pr.deg = deg;
  prologue<<<19008, 256, 0, stream>>>(pr);

  // 2. CSR
  scan16k<<<1, 1024, 0, stream>>>(deg, offs, woff);
  csr_fill<<<EE / 256, 256, 0, stream>>>(ei, woff, csr2);

  // 3. GINE aggregation
  gine_agg<<<NN, 256, 0, stream>>>(eattr, xn_bf, offs, csr2, gine_eps, hin_bf);

  // 4. g_w1 gemm + qh gemm (dual)
  GemmP j_gw1 = {hin_bf, g_w1b, g_b1, NN, 256, 512, GM_F32, nullptr, nullptr, t1f, nullptr};
  GemmP j_qh = {vn_bf, mha_in_wb, mha_in_b, BB * TT, 256, 256, GM_F32, nullptr, nullptr, qhf, nullptr};
  gemm_dual<<<1024 + 8, 256, 0, stream>>>(j_gw1, 1024, 8, j_qh, 4);

  // 5. LN512+gelu
  ln512_gelu<<<NN, 256, 0, stream>>>(t1f, g_lng, g_lnb, t1g_bf);

  // 6. g_w2 gemm -> x1
  GemmP j_gw2 = {t1g_bf, g_w2b, g_b2, NN, 512, 256, GM_RES, x, gamma1, x1f, nullptr};
  gemm_one<<<512, 256, 0, stream>>>(j_gw2, 4);

  // 7. seg_sum + LN3
  mid1<<<256 + NN, 256, 0, stream>>>(x1f, batch, summary, n3_g, n3_b, xn3_bf);

  // 8. build_ctx + q gemm
  GemmP j_q = {xn3_bf, q_wb, q_b, NN, 256, 256, GM_BF16, nullptr, nullptr, nullptr, qx_bf};
  mid2<<<BB * (TT + 1) + 512, 256, 0, stream>>>(summary, cntf, vn_bf, ctx_bf, j_q);

  // 9. kvh gemm (M=264 -> nby=3)
  GemmP j_kvh = {ctx_bf, mha_in_wb + (size_t)256 * 256, mha_in_b + 256, BB * (TT + 1), 256, 512,
                 GM_F32, nullptr, nullptr, kvhf, nullptr};
  gemm_one<<<24, 256, 0, stream>>>(j_kvh, 8);

  // 10. small MHA
  mha_small<<<BB, 256, 0, stream>>>(qhf, kvhf, vatt_bf);

  // 11. mha out gemm -> out_v + vout_bf
  GemmP j_mo = {vatt_bf, mha_out_wb, mha_out_b, BB * TT, 256, 256, GM_RES2, v, gamma2, out_v, vout_bf};
  gemm_one<<<8, 256, 0, stream>>>(j_mo, 4);

  // 12. kv gemm -> kvx
  GemmP j_kv = {vout_bf, kv_wb, kv_b, BB * TT, 256, 512, GM_F32, nullptr, nullptr, kvxf, nullptr};
  gemm_one<<<16, 256, 0, stream>>>(j_kv, 8);

  // 13. cross attention
  cross_attn<<<NN / 16, 256, 0, stream>>>(qx_bf, kvxf, batch, att_bf);

  // 14. o gemm -> x2
  GemmP j_o = {att_bf, o_wb, o_b, NN, 256, 256, GM_RES, x1f, gamma3, x2f, nullptr};
  gemm_one<<<512, 256, 0, stream>>>(j_o, 4);

  // 15. LN4
  ln4_k<<<NN, 256, 0, stream>>>(x2f, n4_g, n4_b, xn4_bf);

  // 16. f_w1 gemm (gelu)
  GemmP j_f1 = {xn4_bf, f_w1b, f_b1, NN, 256, 1024, GM_GELU, nullptr, nullptr, nullptr, u_bf};
  gemm_one<<<2048, 256, 0, stream>>>(j_f1, 16);

  // 17. f_w2 gemm -> out_x
  GemmP j_f2 = {u_bf, f_w2b, f_b2, NN, 1024, 256, GM_RES, x2f, nullptr, out_x, nullptr};
  gemm_one<<<512, 256, 0, stream>>>(j_f2, 4);
}